// Round 9
// baseline (225.441 us; speedup 1.0000x reference)
//
#include <hip/hip_runtime.h>
#include <cstdint>

// ---------------------------------------------------------------------------
// RotationScan: theta/retain/inp GEMM -> chunked complex scan -> out GEMM -> LN
// B=4 T=4096 D=1024 SD=512 CHUNK=32
// ---------------------------------------------------------------------------

typedef __bf16 bf16x8 __attribute__((ext_vector_type(8)));
typedef float  f32x16 __attribute__((ext_vector_type(16)));
typedef ushort u16x8  __attribute__((ext_vector_type(8)));

#define AS1 __attribute__((address_space(1)))
#define AS3 __attribute__((address_space(3)))

__device__ __forceinline__ void gload16(const void* g, void* l) {
  __builtin_amdgcn_global_load_lds((const AS1 void*)g, (AS3 void*)l, 16, 0, 0);
}

__device__ __forceinline__ ushort f2bf(float f) {
  union { float f; uint32_t u; } v; v.f = f;
  uint32_t u = v.u;
  uint32_t r = u + 0x7FFFu + ((u >> 16) & 1u);   // RNE
  return (ushort)(r >> 16);
}
__device__ __forceinline__ float bf2f(ushort u) {
  union { uint32_t x; float f; } v; v.x = (uint32_t)u << 16; return v.f;
}

// ---------------------------------------------------------------------------
// Transpose + f32->bf16 convert:  dst[(row_off + c)*R + r] = bf16(src[r*C + c])
// ---------------------------------------------------------------------------
__global__ __launch_bounds__(256) void tconv(const float* __restrict__ src, int R, int C,
                                             ushort* __restrict__ dst, int row_off) {
  __shared__ float tile[32][33];
  int tx = threadIdx.x, ty = threadIdx.y;
  int rb = blockIdx.y * 32, cb = blockIdx.x * 32;
#pragma unroll
  for (int yy = 0; yy < 4; ++yy) {
    int r = rb + ty + yy * 8;
    tile[ty + yy * 8][tx] = src[(size_t)r * C + cb + tx];
  }
  __syncthreads();
#pragma unroll
  for (int yy = 0; yy < 4; ++yy) {
    int c = cb + ty + yy * 8;
    dst[(size_t)(row_off + c) * R + rb + tx] = f2bf(tile[tx][ty + yy * 8]);
  }
}

__global__ __launch_bounds__(256) void pack_bias(const float* __restrict__ bt,
                                                 const float* __restrict__ br,
                                                 const float* __restrict__ bi,
                                                 float* __restrict__ bcat) {
  int i = blockIdx.x * 256 + threadIdx.x;          // 0..2047
  bcat[i] = (i < 512) ? bt[i] : (i < 1024 ? br[i - 512] : bi[i - 1024]);
}

__global__ __launch_bounds__(256) void xconv(const float4* __restrict__ src,
                                             ushort* __restrict__ dst, int n4) {
  int i = blockIdx.x * 256 + threadIdx.x;
  if (i < n4) {
    float4 v = src[i];
    ushort4 o;
    o.x = f2bf(v.x); o.y = f2bf(v.y); o.z = f2bf(v.z); o.w = f2bf(v.w);
    *(ushort4*)(dst + (size_t)i * 4) = o;
  }
}

// ---------------------------------------------------------------------------
// BM x 256 tile (BM = 256 or 128), BK=64, 8 waves (2Mx4N), double-buffered LDS.
// r7-verified skeleton: 4 fine phases, 2 barriers/K-tile, counted vmcnt.
// THIS ROUND: inner loop switched to v_mfma_f32_32x32x16_bf16 (µbench 2495 TF
// = 99.8% dense peak vs 2176 for 16x16x32): halves MFMA instruction count,
// halves B-fragment ds_reads, halves setprio pairs.
//
// Fragment mapping (guide m74/m101-verified):
//   A/B: lane l -> row l&31, k = (l>>5)*8 + j  -> LDS chunk (ks*2+hk)^(row&7)
//   C/D: col = l&31, row = (reg&3) + 8*(reg>>2) + 4*(l>>5), reg 0..15
// Per wave per K-tile: BM=256: 4 mi x 2 nj x 4 ks = 32 MFMA (phase = mi);
//   BM=128: 2 mi x 2 nj x 4 ks = 16 MFMA (phase = (mi, ks-half)).
// A-pass needs per phase unchanged vs r7 -> vmcnt ledger carries over:
//   BM=256: P0 stage B0,B1(kt+1), wait vmcnt(4) [tail 2]; P1 stage B2,B3;
//           P2 stage A0,A2, wait vmcnt(6) [tail 0]; P3 stage A1,A3.
//   BM=128: P2:{A0} P3:{A1}; P0 wait vmcnt(2) [tail 0]; P2 barrier only.
// WAR/RAW audit identical to r6/r7 (every wait precedes a barrier shared by
// all waves; staged buffer's readers sealed by a preceding barrier).
//
// Epilogue (r7-verified): C-tile -> LDS with 16B-chunk XOR swizzle, then
// coalesced u16x8 stores (WRITE_SIZE == output bytes, no RMW).
// ---------------------------------------------------------------------------
template <int BM>
__global__ __launch_bounds__(512, 2) void gemm256(const ushort* __restrict__ A,
                                                  const ushort* __restrict__ Bt,
                                                  ushort* __restrict__ C,
                                                  const float* __restrict__ bias,
                                                  int M, int N, int K, int nbn) {
  constexpr int MI_T = BM / 64;          // 32-row acc tiles per wave (4 or 2)
  constexpr int STAGE_USH = 2 * (BM * 64 + 256 * 64);
  constexpr int CT_USH = BM * 256;
  constexpr int SM_USH = (STAGE_USH > CT_USH) ? STAGE_USH : CT_USH;
  __shared__ alignas(16) ushort smem[SM_USH];
  ushort* const As0 = smem;                       // As(buf) = As0 + buf*BM*64
  ushort* const Bs0 = smem + 2 * BM * 64;         // Bs(buf) = Bs0 + buf*256*64

  const int cpx = gridDim.x >> 3;
  const int wg = ((int)blockIdx.x & 7) * cpx + ((int)blockIdx.x >> 3);
  const int bm = wg / nbn, bn = wg % nbn;

  const int t = threadIdx.x;
  const int l = t & 63, w = t >> 6;
  const int wm = w >> 2, wn = w & 3;              // wave grid 2(M) x 4(N)
  const int l31 = l & 31, hk = l >> 5;

  const size_t a0 = (size_t)bm * BM * K;
  const size_t b0 = (size_t)bn * 256 * K;

  const int srow = t >> 3;                        // 0..63
  const int sslot = (t & 7) ^ (srow & 7);
  const ushort* gA = A + a0 + (size_t)srow * K + sslot * 8;
  const ushort* gB = Bt + b0 + (size_t)srow * K + sslot * 8;
  const int lboff = w * 1024 + l * 16;            // LDS byte offset in a pass

  f32x16 acc[MI_T][2] = {};
  const int NKT = K >> 6;

#define STGA(buf, kt, u) \
  gload16(gA + (size_t)((u) * 64) * K + (size_t)(kt) * 64, \
          (char*)(As0 + (buf) * BM * 64) + (u) * 8192 + lboff)
#define STGB(buf, kt, u) \
  gload16(gB + (size_t)((u) * 64) * K + (size_t)(kt) * 64, \
          (char*)(Bs0 + (buf) * 256 * 64) + (u) * 8192 + lboff)

  // Phase compute cluster: BM=256 -> mi=ph, ks 0..3; BM=128 -> mi=ph>>1,
  // ks = (ph&1)*2 .. +1.  aF read fresh per phase; bF cached from P0.
#define QUAD(ph)                                                               \
  {                                                                            \
    constexpr int mi_ = (BM == 256) ? (ph) : ((ph) >> 1);                      \
    constexpr int ks0_ = (BM == 256) ? 0 : ((ph) & 1) * 2;                     \
    constexpr int nks_ = (BM == 256) ? 4 : 2;                                  \
    bf16x8 aF[nks_];                                                           \
    const int rowa_ = wm * (BM / 2) + mi_ * 32 + l31;                          \
    _Pragma("unroll")                                                          \
    for (int k2 = 0; k2 < nks_; ++k2) {                                        \
      const int j = ((ks0_ + k2) * 2 + hk) ^ (rowa_ & 7);                      \
      aF[k2] = *(const bf16x8*)&pA[rowa_ * 64 + j * 8];                        \
    }                                                                          \
    __builtin_amdgcn_s_setprio(1);                                             \
    _Pragma("unroll")                                                          \
    for (int nj = 0; nj < 2; ++nj)                                             \
      _Pragma("unroll")                                                        \
      for (int k2 = 0; k2 < nks_; ++k2)                                        \
        acc[mi_][nj] = __builtin_amdgcn_mfma_f32_32x32x16_bf16(                \
            aF[k2], bF[nj][ks0_ + k2], acc[mi_][nj], 0, 0, 0);                 \
    __builtin_amdgcn_s_setprio(0);                                             \
  }

  // prologue: tile 0 in ledger order
  STGB(0, 0, 0); STGB(0, 0, 1); STGB(0, 0, 2); STGB(0, 0, 3);
  if constexpr (BM == 256) { STGA(0, 0, 0); STGA(0, 0, 2); STGA(0, 0, 1); STGA(0, 0, 3); }
  else                     { STGA(0, 0, 0); STGA(0, 0, 1); }

  for (int kt = 0; kt < NKT; ++kt) {
    const int cur = kt & 1, nxt = cur ^ 1;
    const bool hn = (kt + 1 < NKT);
    const ushort* pA = As0 + cur * BM * 64;
    const ushort* pB = Bs0 + cur * 256 * 64;
    // ---------------- phase 0 ----------------
    if (hn) { STGB(nxt, kt + 1, 0); STGB(nxt, kt + 1, 1); }
    if constexpr (BM == 256) {
      if (hn) asm volatile("s_waitcnt vmcnt(4)" ::: "memory");
      else    asm volatile("s_waitcnt vmcnt(2)" ::: "memory");
    } else {
      if (hn) asm volatile("s_waitcnt vmcnt(2)" ::: "memory");
      else    asm volatile("s_waitcnt vmcnt(0)" ::: "memory");
    }
    __builtin_amdgcn_s_barrier();
    asm volatile("" ::: "memory");
    bf16x8 bF[2][4];
#pragma unroll
    for (int nj = 0; nj < 2; ++nj) {
      const int rowb = wn * 64 + nj * 32 + l31;
#pragma unroll
      for (int ks = 0; ks < 4; ++ks) {
        const int j = (ks * 2 + hk) ^ (rowb & 7);
        bF[nj][ks] = *(const bf16x8*)&pB[rowb * 64 + j * 8];
      }
    }
    QUAD(0);
    // ---------------- phase 1 ----------------
    if (hn) { STGB(nxt, kt + 1, 2); STGB(nxt, kt + 1, 3); }
    QUAD(1);
    // ---------------- phase 2 ----------------
    if (hn) {
      if constexpr (BM == 256) { STGA(nxt, kt + 1, 0); STGA(nxt, kt + 1, 2); }
      else                     { STGA(nxt, kt + 1, 0); }
    }
    if constexpr (BM == 256) {
      if (hn) asm volatile("s_waitcnt vmcnt(6)" ::: "memory");
      else    asm volatile("s_waitcnt vmcnt(0)" ::: "memory");
    }
    __builtin_amdgcn_s_barrier();
    asm volatile("" ::: "memory");
    QUAD(2);
    // ---------------- phase 3 ----------------
    if (hn) {
      if constexpr (BM == 256) { STGA(nxt, kt + 1, 1); STGA(nxt, kt + 1, 3); }
      else                     { STGA(nxt, kt + 1, 1); }
    }
    QUAD(3);
  }
#undef STGA
#undef STGB
#undef QUAD

  // ---- epilogue via LDS: swizzled scatter, then coalesced 16B stores ----
  asm volatile("s_waitcnt lgkmcnt(0) vmcnt(0)" ::: "memory");
  __builtin_amdgcn_s_barrier();                   // all waves done with stage LDS

  float bvj[2];
#pragma unroll
  for (int nj = 0; nj < 2; ++nj) {
    const int col = wn * 64 + nj * 32 + l31;
    bvj[nj] = bias ? bias[bn * 256 + col] : 0.f;
  }
#pragma unroll
  for (int mi = 0; mi < MI_T; ++mi) {
#pragma unroll
    for (int nj = 0; nj < 2; ++nj) {
      const int col = wn * 64 + nj * 32 + l31;
      const int chunk = col >> 3;
#pragma unroll
      for (int reg = 0; reg < 16; ++reg) {
        const int rowl = wm * (BM / 2) + mi * 32 + (reg & 3) + 8 * (reg >> 2) + 4 * hk;
        const int pch = chunk ^ (rowl & 7);
        smem[rowl * 256 + pch * 8 + (col & 7)] = f2bf(acc[mi][nj][reg] + bvj[nj]);
      }
    }
  }
  __builtin_amdgcn_s_barrier();

  const int rrow0 = t >> 5;                       // 0..15
  const int rch = t & 31;                         // logical 16B chunk
#pragma unroll
  for (int p = 0; p < BM / 16; ++p) {
    const int rowl = p * 16 + rrow0;
    const int pch = rch ^ (rowl & 7);
    u16x8 vv = *(const u16x8*)&smem[rowl * 256 + pch * 8];
    const size_t grow = (size_t)(bm * BM + rowl);
    *(u16x8*)&C[grow * N + bn * 256 + rch * 8] = vv;
  }
}

// ---------------------------------------------------------------------------
// Scan kernels. lin[row, 2048] (bf16): [theta | retain_logit | inp_r | inp_i]
// cum_mag as running product (== exp(cumsum(log(clip(rt,1e-6)))) within fp32
// noise); the 1e-8 clip on the inverse is preserved exactly.
// ---------------------------------------------------------------------------
__global__ __launch_bounds__(256) void scan_k1(const ushort* __restrict__ lin,
                                               float4* __restrict__ agg) {
  int bd = blockIdx.x * 256 + threadIdx.x;    // 0..2047  (b*512 + d)
  int c  = blockIdx.y;                         // 0..127
  int b  = bd >> 9, d = bd & 511;
  const ushort* base = lin + ((size_t)b * 4096 + (size_t)c * 32) * 2048;
  float cth = 0.f, cbr = 0.f, cbi = 0.f;
  float cm = 1.f, cs = 1.f, sn = 0.f;
#pragma unroll 4
  for (int t = 0; t < 32; ++t) {
    const ushort* row = base + (size_t)t * 2048;
    float th = bf2f(row[d]);
    float z  = bf2f(row[512 + d]);
    float ir = bf2f(row[1024 + d]);
    float ii = bf2f(row[1536 + d]);
    float rt = __fdividef(1.f, 1.f + __expf(-z));
    cm *= fmaxf(rt, 1e-6f);
    cth += th;
    float s_, c_;
    __sincosf(cth, &s_, &c_);
    float im = __fdividef(1.f, fmaxf(cm, 1e-8f));
    float invr = im * c_, invi = -im * s_;
    float drive = 1.f - rt;
    float br_ = drive * ir, bi_ = drive * ii;
    cbr += invr * br_ - invi * bi_;
    cbi += invr * bi_ + invi * br_;
    cs = c_; sn = s_;
  }
  agg[(size_t)c * 2048 + bd] = make_float4(cm * cs, cm * sn, cbr, cbi);
}

__global__ __launch_bounds__(256) void scan_k2(const float4* __restrict__ agg,
                                               float2* __restrict__ h0) {
  int bd = blockIdx.x * 256 + threadIdx.x;    // 2048 threads
  float hr = 0.f, hi = 0.f;
  for (int cg = 0; cg < 16; ++cg) {
    float4 a[8];
#pragma unroll
    for (int u = 0; u < 8; ++u) a[u] = agg[(size_t)(cg * 8 + u) * 2048 + bd];
#pragma unroll
    for (int u = 0; u < 8; ++u) {
      h0[(size_t)(cg * 8 + u) * 2048 + bd] = make_float2(hr, hi);
      float tr = hr + a[u].z, ti = hi + a[u].w;
      hr = a[u].x * tr - a[u].y * ti;
      hi = a[u].x * ti + a[u].y * tr;
    }
  }
}

__global__ __launch_bounds__(256) void scan_k3(const ushort* __restrict__ lin,
                                               const float2* __restrict__ h0,
                                               ushort* __restrict__ outb) {
  int bd = blockIdx.x * 256 + threadIdx.x;
  int c  = blockIdx.y;
  int b  = bd >> 9, d = bd & 511;
  const ushort* base = lin + ((size_t)b * 4096 + (size_t)c * 32) * 2048;
  float2 h = h0[(size_t)c * 2048 + bd];
  float cth = 0.f, cbr = 0.f, cbi = 0.f, cm = 1.f;
#pragma unroll 4
  for (int t = 0; t < 32; ++t) {
    const ushort* row = base + (size_t)t * 2048;
    float th = bf2f(row[d]);
    float z  = bf2f(row[512 + d]);
    float ir = bf2f(row[1024 + d]);
    float ii = bf2f(row[1536 + d]);
    float rt = __fdividef(1.f, 1.f + __expf(-z));
    cm *= fmaxf(rt, 1e-6f);
    cth += th;
    float s_, c_;
    __sincosf(cth, &s_, &c_);
    float im = __fdividef(1.f, fmaxf(cm, 1e-8f));
    float invr = im * c_, invi = -im * s_;
    float drive = 1.f - rt;
    float br_ = drive * ir, bi_ = drive * ii;
    cbr += invr * br_ - invi * bi_;
    cbi += invr * bi_ + invi * br_;
    float ar = cm * c_, ai = cm * s_;
    float tr = h.x + cbr, ti = h.y + cbi;
    float orr = ar * tr - ai * ti;
    float oii = ar * ti + ai * tr;
    size_t rowo = ((size_t)b * 4096 + (size_t)c * 32 + t) * 1024;
    outb[rowo + d] = f2bf(orr);
    outb[rowo + 512 + d] = f2bf(oii);
  }
}

// ---------------------------------------------------------------------------
// LayerNorm over D=1024, one block per row; y = yb + xb (residual fused here).
// ---------------------------------------------------------------------------
__global__ __launch_bounds__(256) void ln_k(const ushort* __restrict__ yb,
                                            const ushort* __restrict__ xb,
                                            const float* __restrict__ gamma,
                                            const float* __restrict__ beta,
                                            float* __restrict__ out) {
  int row = blockIdx.x;
  ushort4 uy = ((const ushort4*)(yb + (size_t)row * 1024))[threadIdx.x];
  ushort4 ux = ((const ushort4*)(xb + (size_t)row * 1024))[threadIdx.x];
  float4 v;
  v.x = bf2f(uy.x) + bf2f(ux.x);
  v.y = bf2f(uy.y) + bf2f(ux.y);
  v.z = bf2f(uy.z) + bf2f(ux.z);
  v.w = bf2f(uy.w) + bf2f(ux.w);
  float s  = v.x + v.y + v.z + v.w;
  float s2 = v.x * v.x + v.y * v.y + v.z * v.z + v.w * v.w;
#pragma unroll
  for (int off = 32; off > 0; off >>= 1) {
    s  += __shfl_down(s, off);
    s2 += __shfl_down(s2, off);
  }
  __shared__ float red[8];
  __shared__ float mv[2];
  int l = threadIdx.x & 63, w = threadIdx.x >> 6;
  if (l == 0) { red[w] = s; red[4 + w] = s2; }
  __syncthreads();
  if (threadIdx.x == 0) {
    float ts = red[0] + red[1] + red[2] + red[3];
    float t2 = red[4] + red[5] + red[6] + red[7];
    float mu = ts * (1.f / 1024.f);
    float var = t2 * (1.f / 1024.f) - mu * mu;
    mv[0] = mu;
    mv[1] = 1.f / sqrtf(var + 1e-5f);
  }
  __syncthreads();
  float mu = mv[0], rstd = mv[1];
  const float4* g4 = (const float4*)gamma;
  const float4* b4 = (const float4*)beta;
  float4 gv = g4[threadIdx.x], bv = b4[threadIdx.x];
  float4 o;
  o.x = (v.x - mu) * rstd * gv.x + bv.x;
  o.y = (v.y - mu) * rstd * gv.y + bv.y;
  o.z = (v.z - mu) * rstd * gv.z + bv.z;
  o.w = (v.w - mu) * rstd * gv.w + bv.w;
  ((float4*)(out + (size_t)row * 1024))[threadIdx.x] = o;
}

// ---------------------------------------------------------------------------
extern "C" void kernel_launch(void* const* d_in, const int* in_sizes, int n_in,
                              void* d_out, int out_size, void* d_ws, size_t ws_size,
                              hipStream_t stream) {
  (void)in_sizes; (void)n_in; (void)out_size; (void)ws_size;
  const float* x  = (const float*)d_in[0];
  const float* Wt = (const float*)d_in[1];
  const float* bt = (const float*)d_in[2];
  const float* Wr = (const float*)d_in[3];
  const float* br = (const float*)d_in[4];
  const float* Wi = (const float*)d_in[5];
  const float* bi = (const float*)d_in[6];
  const float* Wo = (const float*)d_in[7];
  const float* bo = (const float*)d_in[8];
  const float* gamma = (const float*)d_in[9];
  const float* beta  = (const float*)d_in[10];

  char* ws = (char*)d_ws;
  ushort* wcat_t = (ushort*)(ws);                      //  4 MiB: [2048][1024] bf16
  ushort* wo_t   = (ushort*)(ws + ((size_t)4  << 20)); //  2 MiB: [1024][1024] bf16
  float*  bcat   = (float*) (ws + ((size_t)6  << 20)); //  8 KiB
  float4* agg    = (float4*)(ws + ((size_t)8  << 20)); //  4 MiB: [128][2048]
  float2* h0     = (float2*)(ws + ((size_t)12 << 20)); //  2 MiB: [128][2048]
  ushort* xb     = (ushort*)(ws + ((size_t)16 << 20)); // 32 MiB: x bf16 (alive thru ln_k)
  ushort* outb   = (ushort*)(ws + ((size_t)48 << 20)); // 32 MiB: scan out bf16
  ushort* linb   = (ushort*)(ws + ((size_t)80 << 20)); // 64 MiB: lin bf16
  ushort* yb     = (ushort*)(ws + ((size_t)80 << 20)); // 32 MiB: y bf16 (overlays dead linb)

  // weight prep
  tconv<<<dim3(512 / 32, 1024 / 32), dim3(32, 8), 0, stream>>>(Wt, 1024, 512, wcat_t, 0);
  tconv<<<dim3(512 / 32, 1024 / 32), dim3(32, 8), 0, stream>>>(Wr, 1024, 512, wcat_t, 512);
  tconv<<<dim3(1024 / 32, 1024 / 32), dim3(32, 8), 0, stream>>>(Wi, 1024, 1024, wcat_t, 1024);
  tconv<<<dim3(1024 / 32, 1024 / 32), dim3(32, 8), 0, stream>>>(Wo, 1024, 1024, wo_t, 0);
  pack_bias<<<8, 256, 0, stream>>>(bt, br, bi, bcat);
  xconv<<<16384, 256, 0, stream>>>((const float4*)x, xb, 4194304);

  // lin(bf16) = x @ [Wt|Wr|Wi] + [bt|br|bi]   (M=16384 N=2048 K=1024, 512 blocks)
  gemm256<256><<<512, 512, 0, stream>>>(xb, wcat_t, linb, bcat, 16384, 2048, 1024, 8);

  // chunked complex scan
  scan_k1<<<dim3(8, 128), 256, 0, stream>>>(linb, agg);
  scan_k2<<<8, 256, 0, stream>>>(agg, h0);
  scan_k3<<<dim3(8, 128), 256, 0, stream>>>(linb, h0, outb);

  // yb(bf16) = out @ Wo + bo   (M=16384 N=1024 K=1024, 512 blocks of 128x256)
  gemm256<128><<<512, 512, 0, stream>>>(outb, wo_t, yb, bo, 16384, 1024, 1024, 4);

  // layernorm(yb + xb) -> d_out
  ln_k<<<16384, 256, 0, stream>>>(yb, xb, gamma, beta, (float*)d_out);
}

// Round 10
// 210.590 us; speedup vs baseline: 1.0705x; 1.0705x over previous
//
#include <hip/hip_runtime.h>
#include <cstdint>

// ---------------------------------------------------------------------------
// RotationScan: theta/retain/inp GEMM -> chunked complex scan -> out GEMM -> LN
// B=4 T=4096 D=1024 SD=512 CHUNK=32
// r10 = r7 kernel (session best, 213.3us) + GEMM2 moved to the BM=256 path
// (one dispatch round, 256 blocks). r9's 32x32 MFMA reverted (4-way LDS
// bank conflict: 6.29M counted).
// ---------------------------------------------------------------------------

typedef __bf16 bf16x8 __attribute__((ext_vector_type(8)));
typedef float  f32x4  __attribute__((ext_vector_type(4)));
typedef ushort u16x8  __attribute__((ext_vector_type(8)));

#define AS1 __attribute__((address_space(1)))
#define AS3 __attribute__((address_space(3)))

__device__ __forceinline__ void gload16(const void* g, void* l) {
  __builtin_amdgcn_global_load_lds((const AS1 void*)g, (AS3 void*)l, 16, 0, 0);
}

__device__ __forceinline__ ushort f2bf(float f) {
  union { float f; uint32_t u; } v; v.f = f;
  uint32_t u = v.u;
  uint32_t r = u + 0x7FFFu + ((u >> 16) & 1u);   // RNE
  return (ushort)(r >> 16);
}
__device__ __forceinline__ float bf2f(ushort u) {
  union { uint32_t x; float f; } v; v.x = (uint32_t)u << 16; return v.f;
}

// ---------------------------------------------------------------------------
// Transpose + f32->bf16 convert:  dst[(row_off + c)*R + r] = bf16(src[r*C + c])
// ---------------------------------------------------------------------------
__global__ __launch_bounds__(256) void tconv(const float* __restrict__ src, int R, int C,
                                             ushort* __restrict__ dst, int row_off) {
  __shared__ float tile[32][33];
  int tx = threadIdx.x, ty = threadIdx.y;
  int rb = blockIdx.y * 32, cb = blockIdx.x * 32;
#pragma unroll
  for (int yy = 0; yy < 4; ++yy) {
    int r = rb + ty + yy * 8;
    tile[ty + yy * 8][tx] = src[(size_t)r * C + cb + tx];
  }
  __syncthreads();
#pragma unroll
  for (int yy = 0; yy < 4; ++yy) {
    int c = cb + ty + yy * 8;
    dst[(size_t)(row_off + c) * R + rb + tx] = f2bf(tile[tx][ty + yy * 8]);
  }
}

__global__ __launch_bounds__(256) void pack_bias(const float* __restrict__ bt,
                                                 const float* __restrict__ br,
                                                 const float* __restrict__ bi,
                                                 float* __restrict__ bcat) {
  int i = blockIdx.x * 256 + threadIdx.x;          // 0..2047
  bcat[i] = (i < 512) ? bt[i] : (i < 1024 ? br[i - 512] : bi[i - 1024]);
}

__global__ __launch_bounds__(256) void xconv(const float4* __restrict__ src,
                                             ushort* __restrict__ dst, int n4) {
  int i = blockIdx.x * 256 + threadIdx.x;
  if (i < n4) {
    float4 v = src[i];
    ushort4 o;
    o.x = f2bf(v.x); o.y = f2bf(v.y); o.z = f2bf(v.z); o.w = f2bf(v.w);
    *(ushort4*)(dst + (size_t)i * 4) = o;
  }
}

// ---------------------------------------------------------------------------
// BM x 256 tile (BM = 256 or 128), BK=64, 8 waves (2Mx4N), double-buffered LDS.
// 4 fine phases per K-tile, 2 barriers per K-tile, counted vmcnt (r6-verified
// ledger). 16x16x32 MFMA + chunk^(row&7) swizzle (verified conflict-free).
//
// BM=256 (8 gloads/tile): P0:{B0,B1} P1:{B2,B3} P2:{A0,A2} P3:{A1,A3};
//   waits: P0 vmcnt(4) [tail 2], P2 vmcnt(6) [tail 0].
// BM=128 (6 gloads/tile): P0:{B0,B1} P1:{B2,B3} P2:{A0} P3:{A1};
//   P0 wait vmcnt(2) non-tail, tail vmcnt(0). P2: barrier only.
// WAR: Bs[nxt] staged P0/P1, last read kt-1.P0, sealed by kt-1.P2 barrier;
//   As[nxt] staged P2/P3, last read kt-1 QUADs, sealed by kt.P0 barrier;
//   Bs[cur] staged by fast waves at kt+1.P0, bF reads sealed by kt.P2 barrier.
//
// Epilogue (r7-verified): C-tile -> LDS with 16B-chunk XOR swizzle, then
// coalesced u16x8 stores (full 64B lines; WRITE_SIZE == output bytes).
// ---------------------------------------------------------------------------
template <int BM>
__global__ __launch_bounds__(512, 2) void gemm256(const ushort* __restrict__ A,
                                                  const ushort* __restrict__ Bt,
                                                  ushort* __restrict__ C,
                                                  const float* __restrict__ bias,
                                                  int M, int N, int K, int nbn) {
  constexpr int MI = BM / 32;            // acc row-groups per wave (8 or 4)
  constexpr int II = BM / 128;           // row-groups per phase (2 or 1)
  constexpr int STAGE_USH = 2 * (BM * 64 + 256 * 64);
  constexpr int CT_USH = BM * 256;
  constexpr int SM_USH = (STAGE_USH > CT_USH) ? STAGE_USH : CT_USH;
  __shared__ alignas(16) ushort smem[SM_USH];
  ushort* const As0 = smem;                       // As(buf) = As0 + buf*BM*64
  ushort* const Bs0 = smem + 2 * BM * 64;         // Bs(buf) = Bs0 + buf*256*64

  const int cpx = gridDim.x >> 3;
  const int wg = ((int)blockIdx.x & 7) * cpx + ((int)blockIdx.x >> 3);
  const int bm = wg / nbn, bn = wg % nbn;

  const int t = threadIdx.x;
  const int l = t & 63, w = t >> 6;
  const int wm = w >> 2, wn = w & 3;              // wave grid 2(M) x 4(N)
  const int r = l & 15, kq = l >> 4;

  const size_t a0 = (size_t)bm * BM * K;
  const size_t b0 = (size_t)bn * 256 * K;

  const int srow = t >> 3;                        // 0..63
  const int sslot = (t & 7) ^ (srow & 7);
  const ushort* gA = A + a0 + (size_t)srow * K + sslot * 8;
  const ushort* gB = Bt + b0 + (size_t)srow * K + sslot * 8;
  const int lboff = w * 1024 + l * 16;            // LDS byte offset in a pass

  f32x4 acc[MI][4] = {};
  const int NKT = K >> 6;

#define STGA(buf, kt, u) \
  gload16(gA + (size_t)((u) * 64) * K + (size_t)(kt) * 64, \
          (char*)(As0 + (buf) * BM * 64) + (u) * 8192 + lboff)
#define STGB(buf, kt, u) \
  gload16(gB + (size_t)((u) * 64) * K + (size_t)(kt) * 64, \
          (char*)(Bs0 + (buf) * 256 * 64) + (u) * 8192 + lboff)

#define QUAD(ph)                                                               \
  do {                                                                         \
    _Pragma("unroll")                                                          \
    for (int ii = 0; ii < II; ++ii) {                                          \
      bf16x8 aF[2];                                                            \
      const int rowa = wm * (BM / 2) + ((ph) * II + ii) * 16 + r;              \
      _Pragma("unroll")                                                        \
      for (int ks = 0; ks < 2; ++ks) {                                         \
        const int j = (ks * 4 + kq) ^ (r & 7);                                 \
        aF[ks] = *(const bf16x8*)&pA[rowa * 64 + j * 8];                       \
      }                                                                        \
      __builtin_amdgcn_s_setprio(1);                                           \
      _Pragma("unroll")                                                        \
      for (int jn = 0; jn < 4; ++jn)                                           \
        _Pragma("unroll")                                                      \
        for (int ks = 0; ks < 2; ++ks)                                         \
          acc[(ph) * II + ii][jn] = __builtin_amdgcn_mfma_f32_16x16x32_bf16(   \
              aF[ks], bF[jn][ks], acc[(ph) * II + ii][jn], 0, 0, 0);           \
      __builtin_amdgcn_s_setprio(0);                                           \
    }                                                                          \
  } while (0)

  // prologue: tile 0 in ledger order
  STGB(0, 0, 0); STGB(0, 0, 1); STGB(0, 0, 2); STGB(0, 0, 3);
  if constexpr (BM == 256) { STGA(0, 0, 0); STGA(0, 0, 2); STGA(0, 0, 1); STGA(0, 0, 3); }
  else                     { STGA(0, 0, 0); STGA(0, 0, 1); }

  for (int kt = 0; kt < NKT; ++kt) {
    const int cur = kt & 1, nxt = cur ^ 1;
    const bool hn = (kt + 1 < NKT);
    const ushort* pA = As0 + cur * BM * 64;
    const ushort* pB = Bs0 + cur * 256 * 64;
    // ---------------- phase 0 ----------------
    if (hn) { STGB(nxt, kt + 1, 0); STGB(nxt, kt + 1, 1); }
    if constexpr (BM == 256) {
      if (hn) asm volatile("s_waitcnt vmcnt(4)" ::: "memory");
      else    asm volatile("s_waitcnt vmcnt(2)" ::: "memory");
    } else {
      if (hn) asm volatile("s_waitcnt vmcnt(2)" ::: "memory");
      else    asm volatile("s_waitcnt vmcnt(0)" ::: "memory");
    }
    __builtin_amdgcn_s_barrier();
    asm volatile("" ::: "memory");
    bf16x8 bF[4][2];
#pragma unroll
    for (int jn = 0; jn < 4; ++jn) {
      const int rowb = wn * 64 + jn * 16 + r;
#pragma unroll
      for (int ks = 0; ks < 2; ++ks) {
        const int j = (ks * 4 + kq) ^ (r & 7);
        bF[jn][ks] = *(const bf16x8*)&pB[rowb * 64 + j * 8];
      }
    }
    QUAD(0);
    // ---------------- phase 1 ----------------
    if (hn) { STGB(nxt, kt + 1, 2); STGB(nxt, kt + 1, 3); }
    QUAD(1);
    // ---------------- phase 2 ----------------
    if (hn) {
      if constexpr (BM == 256) { STGA(nxt, kt + 1, 0); STGA(nxt, kt + 1, 2); }
      else                     { STGA(nxt, kt + 1, 0); }
    }
    if constexpr (BM == 256) {
      if (hn) asm volatile("s_waitcnt vmcnt(6)" ::: "memory");
      else    asm volatile("s_waitcnt vmcnt(0)" ::: "memory");
    }
    __builtin_amdgcn_s_barrier();
    asm volatile("" ::: "memory");
    QUAD(2);
    // ---------------- phase 3 ----------------
    if (hn) {
      if constexpr (BM == 256) { STGA(nxt, kt + 1, 1); STGA(nxt, kt + 1, 3); }
      else                     { STGA(nxt, kt + 1, 1); }
    }
    QUAD(3);
  }
#undef STGA
#undef STGB
#undef QUAD

  // ---- epilogue via LDS: swizzled scatter, then coalesced 16B stores ----
  asm volatile("s_waitcnt lgkmcnt(0) vmcnt(0)" ::: "memory");
  __builtin_amdgcn_s_barrier();                   // all waves done with stage LDS

  const int q4 = (l >> 4) * 4;
  float bvj[4];
#pragma unroll
  for (int jn = 0; jn < 4; ++jn) {
    const int col = wn * 64 + jn * 16 + r;
    bvj[jn] = bias ? bias[bn * 256 + col] : 0.f;
  }
#pragma unroll
  for (int i = 0; i < MI; ++i) {
#pragma unroll
    for (int jn = 0; jn < 4; ++jn) {
      const int col = wn * 64 + jn * 16 + r;
      const int chunk = col >> 3;
#pragma unroll
      for (int q = 0; q < 4; ++q) {
        const int rowl = wm * (BM / 2) + i * 16 + q4 + q;
        const int pch = chunk ^ (rowl & 7);
        smem[rowl * 256 + pch * 8 + (col & 7)] = f2bf(acc[i][jn][q] + bvj[jn]);
      }
    }
  }
  __builtin_amdgcn_s_barrier();

  const int rrow0 = t >> 5;                       // 0..15
  const int rch = t & 31;                         // logical 16B chunk
#pragma unroll
  for (int p = 0; p < BM / 16; ++p) {
    const int rowl = p * 16 + rrow0;
    const int pch = rch ^ (rowl & 7);
    u16x8 vv = *(const u16x8*)&smem[rowl * 256 + pch * 8];
    const size_t grow = (size_t)(bm * BM + rowl);
    *(u16x8*)&C[grow * N + bn * 256 + rch * 8] = vv;
  }
}

// ---------------------------------------------------------------------------
// Scan kernels. lin[row, 2048] (bf16): [theta | retain_logit | inp_r | inp_i]
// cum_mag as running product (== exp(cumsum(log(clip(rt,1e-6)))) within fp32
// noise); the 1e-8 clip on the inverse is preserved exactly.
// ---------------------------------------------------------------------------
__global__ __launch_bounds__(256) void scan_k1(const ushort* __restrict__ lin,
                                               float4* __restrict__ agg) {
  int bd = blockIdx.x * 256 + threadIdx.x;    // 0..2047  (b*512 + d)
  int c  = blockIdx.y;                         // 0..127
  int b  = bd >> 9, d = bd & 511;
  const ushort* base = lin + ((size_t)b * 4096 + (size_t)c * 32) * 2048;
  float cth = 0.f, cbr = 0.f, cbi = 0.f;
  float cm = 1.f, cs = 1.f, sn = 0.f;
#pragma unroll 4
  for (int t = 0; t < 32; ++t) {
    const ushort* row = base + (size_t)t * 2048;
    float th = bf2f(row[d]);
    float z  = bf2f(row[512 + d]);
    float ir = bf2f(row[1024 + d]);
    float ii = bf2f(row[1536 + d]);
    float rt = __fdividef(1.f, 1.f + __expf(-z));
    cm *= fmaxf(rt, 1e-6f);
    cth += th;
    float s_, c_;
    __sincosf(cth, &s_, &c_);
    float im = __fdividef(1.f, fmaxf(cm, 1e-8f));
    float invr = im * c_, invi = -im * s_;
    float drive = 1.f - rt;
    float br_ = drive * ir, bi_ = drive * ii;
    cbr += invr * br_ - invi * bi_;
    cbi += invr * bi_ + invi * br_;
    cs = c_; sn = s_;
  }
  agg[(size_t)c * 2048 + bd] = make_float4(cm * cs, cm * sn, cbr, cbi);
}

__global__ __launch_bounds__(256) void scan_k2(const float4* __restrict__ agg,
                                               float2* __restrict__ h0) {
  int bd = blockIdx.x * 256 + threadIdx.x;    // 2048 threads
  float hr = 0.f, hi = 0.f;
  for (int cg = 0; cg < 16; ++cg) {
    float4 a[8];
#pragma unroll
    for (int u = 0; u < 8; ++u) a[u] = agg[(size_t)(cg * 8 + u) * 2048 + bd];
#pragma unroll
    for (int u = 0; u < 8; ++u) {
      h0[(size_t)(cg * 8 + u) * 2048 + bd] = make_float2(hr, hi);
      float tr = hr + a[u].z, ti = hi + a[u].w;
      hr = a[u].x * tr - a[u].y * ti;
      hi = a[u].x * ti + a[u].y * tr;
    }
  }
}

__global__ __launch_bounds__(256) void scan_k3(const ushort* __restrict__ lin,
                                               const float2* __restrict__ h0,
                                               ushort* __restrict__ outb) {
  int bd = blockIdx.x * 256 + threadIdx.x;
  int c  = blockIdx.y;
  int b  = bd >> 9, d = bd & 511;
  const ushort* base = lin + ((size_t)b * 4096 + (size_t)c * 32) * 2048;
  float2 h = h0[(size_t)c * 2048 + bd];
  float cth = 0.f, cbr = 0.f, cbi = 0.f, cm = 1.f;
#pragma unroll 4
  for (int t = 0; t < 32; ++t) {
    const ushort* row = base + (size_t)t * 2048;
    float th = bf2f(row[d]);
    float z  = bf2f(row[512 + d]);
    float ir = bf2f(row[1024 + d]);
    float ii = bf2f(row[1536 + d]);
    float rt = __fdividef(1.f, 1.f + __expf(-z));
    cm *= fmaxf(rt, 1e-6f);
    cth += th;
    float s_, c_;
    __sincosf(cth, &s_, &c_);
    float im = __fdividef(1.f, fmaxf(cm, 1e-8f));
    float invr = im * c_, invi = -im * s_;
    float drive = 1.f - rt;
    float br_ = drive * ir, bi_ = drive * ii;
    cbr += invr * br_ - invi * bi_;
    cbi += invr * bi_ + invi * br_;
    float ar = cm * c_, ai = cm * s_;
    float tr = h.x + cbr, ti = h.y + cbi;
    float orr = ar * tr - ai * ti;
    float oii = ar * ti + ai * tr;
    size_t rowo = ((size_t)b * 4096 + (size_t)c * 32 + t) * 1024;
    outb[rowo + d] = f2bf(orr);
    outb[rowo + 512 + d] = f2bf(oii);
  }
}

// ---------------------------------------------------------------------------
// LayerNorm over D=1024, one block per row; y = yb + xb (residual fused here).
// ---------------------------------------------------------------------------
__global__ __launch_bounds__(256) void ln_k(const ushort* __restrict__ yb,
                                            const ushort* __restrict__ xb,
                                            const float* __restrict__ gamma,
                                            const float* __restrict__ beta,
                                            float* __restrict__ out) {
  int row = blockIdx.x;
  ushort4 uy = ((const ushort4*)(yb + (size_t)row * 1024))[threadIdx.x];
  ushort4 ux = ((const ushort4*)(xb + (size_t)row * 1024))[threadIdx.x];
  float4 v;
  v.x = bf2f(uy.x) + bf2f(ux.x);
  v.y = bf2f(uy.y) + bf2f(ux.y);
  v.z = bf2f(uy.z) + bf2f(ux.z);
  v.w = bf2f(uy.w) + bf2f(ux.w);
  float s  = v.x + v.y + v.z + v.w;
  float s2 = v.x * v.x + v.y * v.y + v.z * v.z + v.w * v.w;
#pragma unroll
  for (int off = 32; off > 0; off >>= 1) {
    s  += __shfl_down(s, off);
    s2 += __shfl_down(s2, off);
  }
  __shared__ float red[8];
  __shared__ float mv[2];
  int l = threadIdx.x & 63, w = threadIdx.x >> 6;
  if (l == 0) { red[w] = s; red[4 + w] = s2; }
  __syncthreads();
  if (threadIdx.x == 0) {
    float ts = red[0] + red[1] + red[2] + red[3];
    float t2 = red[4] + red[5] + red[6] + red[7];
    float mu = ts * (1.f / 1024.f);
    float var = t2 * (1.f / 1024.f) - mu * mu;
    mv[0] = mu;
    mv[1] = 1.f / sqrtf(var + 1e-5f);
  }
  __syncthreads();
  float mu = mv[0], rstd = mv[1];
  const float4* g4 = (const float4*)gamma;
  const float4* b4 = (const float4*)beta;
  float4 gv = g4[threadIdx.x], bv = b4[threadIdx.x];
  float4 o;
  o.x = (v.x - mu) * rstd * gv.x + bv.x;
  o.y = (v.y - mu) * rstd * gv.y + bv.y;
  o.z = (v.z - mu) * rstd * gv.z + bv.z;
  o.w = (v.w - mu) * rstd * gv.w + bv.w;
  ((float4*)(out + (size_t)row * 1024))[threadIdx.x] = o;
}

// ---------------------------------------------------------------------------
extern "C" void kernel_launch(void* const* d_in, const int* in_sizes, int n_in,
                              void* d_out, int out_size, void* d_ws, size_t ws_size,
                              hipStream_t stream) {
  (void)in_sizes; (void)n_in; (void)out_size; (void)ws_size;
  const float* x  = (const float*)d_in[0];
  const float* Wt = (const float*)d_in[1];
  const float* bt = (const float*)d_in[2];
  const float* Wr = (const float*)d_in[3];
  const float* br = (const float*)d_in[4];
  const float* Wi = (const float*)d_in[5];
  const float* bi = (const float*)d_in[6];
  const float* Wo = (const float*)d_in[7];
  const float* bo = (const float*)d_in[8];
  const float* gamma = (const float*)d_in[9];
  const float* beta  = (const float*)d_in[10];

  char* ws = (char*)d_ws;
  ushort* wcat_t = (ushort*)(ws);                      //  4 MiB: [2048][1024] bf16
  ushort* wo_t   = (ushort*)(ws + ((size_t)4  << 20)); //  2 MiB: [1024][1024] bf16
  float*  bcat   = (float*) (ws + ((size_t)6  << 20)); //  8 KiB
  float4* agg    = (float4*)(ws + ((size_t)8  << 20)); //  4 MiB: [128][2048]
  float2* h0     = (float2*)(ws + ((size_t)12 << 20)); //  2 MiB: [128][2048]
  ushort* xb     = (ushort*)(ws + ((size_t)16 << 20)); // 32 MiB: x bf16 (alive thru ln_k)
  ushort* outb   = (ushort*)(ws + ((size_t)48 << 20)); // 32 MiB: scan out bf16
  ushort* linb   = (ushort*)(ws + ((size_t)80 << 20)); // 64 MiB: lin bf16
  ushort* yb     = (ushort*)(ws + ((size_t)80 << 20)); // 32 MiB: y bf16 (overlays dead linb)

  // weight prep
  tconv<<<dim3(512 / 32, 1024 / 32), dim3(32, 8), 0, stream>>>(Wt, 1024, 512, wcat_t, 0);
  tconv<<<dim3(512 / 32, 1024 / 32), dim3(32, 8), 0, stream>>>(Wr, 1024, 512, wcat_t, 512);
  tconv<<<dim3(1024 / 32, 1024 / 32), dim3(32, 8), 0, stream>>>(Wi, 1024, 1024, wcat_t, 1024);
  tconv<<<dim3(1024 / 32, 1024 / 32), dim3(32, 8), 0, stream>>>(Wo, 1024, 1024, wo_t, 0);
  pack_bias<<<8, 256, 0, stream>>>(bt, br, bi, bcat);
  xconv<<<16384, 256, 0, stream>>>((const float4*)x, xb, 4194304);

  // lin(bf16) = x @ [Wt|Wr|Wi] + [bt|br|bi]   (M=16384 N=2048 K=1024, 512 blocks)
  gemm256<256><<<512, 512, 0, stream>>>(xb, wcat_t, linb, bcat, 16384, 2048, 1024, 8);

  // chunked complex scan
  scan_k1<<<dim3(8, 128), 256, 0, stream>>>(linb, agg);
  scan_k2<<<8, 256, 0, stream>>>(agg, h0);
  scan_k3<<<dim3(8, 128), 256, 0, stream>>>(linb, h0, outb);

  // yb(bf16) = out @ Wo + bo   (M=16384 N=1024 K=1024, 256 blocks of 256x256,
  // exactly 1 block/CU, single dispatch round)
  gemm256<256><<<256, 512, 0, stream>>>(outb, wo_t, yb, bo, 16384, 1024, 1024, 4);

  // layernorm(yb + xb) -> d_out
  ln_k<<<16384, 256, 0, stream>>>(yb, xb, gamma, beta, (float*)d_out);
}

// Round 11
// 199.325 us; speedup vs baseline: 1.1310x; 1.0565x over previous
//
#include <hip/hip_runtime.h>
#include <cstdint>

// ---------------------------------------------------------------------------
// RotationScan: theta/retain/inp GEMM -> chunked complex scan -> out GEMM -> LN
// B=4 T=4096 D=1024 SD=512 CHUNK=32
// r11 = r10 + GEMM single-publish-barrier schedule (one vmcnt/K-tile, QUAD2
// fragments pre-read before the WAR-spacer barrier) + waveized ln_k + fused
// weight prep.
// ---------------------------------------------------------------------------

typedef __bf16 bf16x8 __attribute__((ext_vector_type(8)));
typedef float  f32x4  __attribute__((ext_vector_type(4)));
typedef ushort u16x8  __attribute__((ext_vector_type(8)));

#define AS1 __attribute__((address_space(1)))
#define AS3 __attribute__((address_space(3)))

__device__ __forceinline__ void gload16(const void* g, void* l) {
  __builtin_amdgcn_global_load_lds((const AS1 void*)g, (AS3 void*)l, 16, 0, 0);
}

__device__ __forceinline__ ushort f2bf(float f) {
  union { float f; uint32_t u; } v; v.f = f;
  uint32_t u = v.u;
  uint32_t r = u + 0x7FFFu + ((u >> 16) & 1u);   // RNE
  return (ushort)(r >> 16);
}
__device__ __forceinline__ float bf2f(ushort u) {
  union { uint32_t x; float f; } v; v.x = (uint32_t)u << 16; return v.f;
}

// ---------------------------------------------------------------------------
// Fused transpose + f32->bf16 for all 4 weights (one launch):
//   z=0: Wt -> wcat rows 0..511     z=1: Wr -> wcat rows 512..1023
//   z=2: Wi -> wcat rows 1024..3071 z=3: Wo -> wot rows 0..1023
// ---------------------------------------------------------------------------
__global__ __launch_bounds__(256) void tconv_all(const float* __restrict__ Wt,
                                                 const float* __restrict__ Wr,
                                                 const float* __restrict__ Wi,
                                                 const float* __restrict__ Wo,
                                                 ushort* __restrict__ wcat,
                                                 ushort* __restrict__ wot) {
  const int z = blockIdx.z;
  if (z < 2 && blockIdx.x >= 16) return;          // C=512 weights: 16 col-blocks
  const float* src = (z == 0) ? Wt : (z == 1) ? Wr : (z == 2) ? Wi : Wo;
  const int C = (z < 2) ? 512 : 1024;
  const int row_off = (z == 0) ? 0 : (z == 1) ? 512 : (z == 2) ? 1024 : 0;
  ushort* dst = (z == 3) ? wot : wcat;

  __shared__ float tile[32][33];
  int tx = threadIdx.x, ty = threadIdx.y;
  int rb = blockIdx.y * 32, cb = blockIdx.x * 32;
#pragma unroll
  for (int yy = 0; yy < 4; ++yy) {
    int r = rb + ty + yy * 8;
    tile[ty + yy * 8][tx] = src[(size_t)r * C + cb + tx];
  }
  __syncthreads();
#pragma unroll
  for (int yy = 0; yy < 4; ++yy) {
    int c = cb + ty + yy * 8;
    dst[(size_t)(row_off + c) * 1024 + rb + tx] = f2bf(tile[tx][ty + yy * 8]);
  }
}

__global__ __launch_bounds__(256) void pack_bias(const float* __restrict__ bt,
                                                 const float* __restrict__ br,
                                                 const float* __restrict__ bi,
                                                 float* __restrict__ bcat) {
  int i = blockIdx.x * 256 + threadIdx.x;          // 0..2047
  bcat[i] = (i < 512) ? bt[i] : (i < 1024 ? br[i - 512] : bi[i - 1024]);
}

__global__ __launch_bounds__(256) void xconv(const float4* __restrict__ src,
                                             ushort* __restrict__ dst, int n4) {
  int i = blockIdx.x * 256 + threadIdx.x;
  if (i < n4) {
    float4 v = src[i];
    ushort4 o;
    o.x = f2bf(v.x); o.y = f2bf(v.y); o.z = f2bf(v.z); o.w = f2bf(v.w);
    *(ushort4*)(dst + (size_t)i * 4) = o;
  }
}

// ---------------------------------------------------------------------------
// 256x256 tile, BK=64, 8 waves (2Mx4N), double-buffered 128 KiB LDS.
// 16x16x32 MFMA + chunk^(row&7) swizzle (verified conflict-free r7/r10).
//
// r11 schedule — ONE publish barrier + ONE WAR-spacer barrier per K-tile:
//  P0: stage B0,B1(kt+1); vmcnt(2) [tail vmcnt(0)] — the 2 newest allowed
//      are exactly B(kt+1)'s pair, so ALL of tile kt (B@P0/P1(kt-1),
//      A@P2/P3(kt-1)) is proven drained; barrier (publish) + clobber;
//      read bF(8)+aF q0(4); 16 MFMA.
//  P1: stage B2,B3(kt+1); read aF q1; 16 MFMA; PRE-READ aF q2 (As[cur] was
//      published at P0 — legal before the next barrier).
//  P2: stage A0,A2(kt+1); clobber + barrier (WAR spacer: pins next iter's
//      B-stage below; all waves' bF reads retired via lgkmcnt before their
//      QUAD1 MFMA, hence before this barrier); 16 MFMA on pre-read q2.
//  P3: stage A1,A3(kt+1); read aF q3; 16 MFMA.
// WAR audit: Bs[cur(kt)] overwritten by B(kt+2)@P0(kt+1) — sealed by P2(kt)
// barrier. As[nxt] overwritten @P2/P3(kt) — last read QUAD3(kt-1), sealed by
// P0(kt) barrier+clobber.
//
// Epilogue (r7-verified): C-tile -> LDS 16B-chunk XOR swizzle -> coalesced
// u16x8 stores (WRITE_SIZE == output bytes).
// ---------------------------------------------------------------------------
__global__ __launch_bounds__(512, 2) void gemm256(const ushort* __restrict__ A,
                                                  const ushort* __restrict__ Bt,
                                                  ushort* __restrict__ C,
                                                  const float* __restrict__ bias,
                                                  int M, int N, int K, int nbn) {
  __shared__ alignas(16) ushort smem[65536];      // stage 128KB == C-tile 128KB
  ushort* const As0 = smem;                       // As(buf) = As0 + buf*256*64
  ushort* const Bs0 = smem + 2 * 256 * 64;        // Bs(buf) = Bs0 + buf*256*64

  const int cpx = gridDim.x >> 3;
  const int wg = ((int)blockIdx.x & 7) * cpx + ((int)blockIdx.x >> 3);
  const int bm = wg / nbn, bn = wg % nbn;

  const int t = threadIdx.x;
  const int l = t & 63, w = t >> 6;
  const int wm = w >> 2, wn = w & 3;              // wave grid 2(M) x 4(N)
  const int r = l & 15, kq = l >> 4;

  const size_t a0 = (size_t)bm * 256 * K;
  const size_t b0 = (size_t)bn * 256 * K;

  const int srow = t >> 3;                        // 0..63
  const int sslot = (t & 7) ^ (srow & 7);
  const ushort* gA = A + a0 + (size_t)srow * K + sslot * 8;
  const ushort* gB = Bt + b0 + (size_t)srow * K + sslot * 8;
  const int lboff = w * 1024 + l * 16;            // LDS byte offset in a pass

  f32x4 acc[8][4] = {};
  const int NKT = K >> 6;

#define STGA(buf, kt, u) \
  gload16(gA + (size_t)((u) * 64) * K + (size_t)(kt) * 64, \
          (char*)(As0 + (buf) * 256 * 64) + (u) * 8192 + lboff)
#define STGB(buf, kt, u) \
  gload16(gB + (size_t)((u) * 64) * K + (size_t)(kt) * 64, \
          (char*)(Bs0 + (buf) * 256 * 64) + (u) * 8192 + lboff)

#define QUAD(ph)                                                               \
  do {                                                                         \
    _Pragma("unroll")                                                          \
    for (int ii = 0; ii < 2; ++ii) {                                           \
      bf16x8 aF[2];                                                            \
      const int rowa = wm * 128 + ((ph) * 2 + ii) * 16 + r;                    \
      _Pragma("unroll")                                                        \
      for (int ks = 0; ks < 2; ++ks) {                                         \
        const int j = (ks * 4 + kq) ^ (r & 7);                                 \
        aF[ks] = *(const bf16x8*)&pA[rowa * 64 + j * 8];                       \
      }                                                                        \
      __builtin_amdgcn_s_setprio(1);                                           \
      _Pragma("unroll")                                                        \
      for (int jn = 0; jn < 4; ++jn)                                           \
        _Pragma("unroll")                                                      \
        for (int ks = 0; ks < 2; ++ks)                                         \
          acc[(ph) * 2 + ii][jn] = __builtin_amdgcn_mfma_f32_16x16x32_bf16(    \
              aF[ks], bF[jn][ks], acc[(ph) * 2 + ii][jn], 0, 0, 0);            \
      __builtin_amdgcn_s_setprio(0);                                           \
    }                                                                          \
  } while (0)

  // prologue: tile 0 in ledger order
  STGB(0, 0, 0); STGB(0, 0, 1); STGB(0, 0, 2); STGB(0, 0, 3);
  STGA(0, 0, 0); STGA(0, 0, 2); STGA(0, 0, 1); STGA(0, 0, 3);

  for (int kt = 0; kt < NKT; ++kt) {
    const int cur = kt & 1, nxt = cur ^ 1;
    const bool hn = (kt + 1 < NKT);
    const ushort* pA = As0 + cur * 256 * 64;
    const ushort* pB = Bs0 + cur * 256 * 64;

    // ---------------- phase 0 (publish) ----------------
    if (hn) { STGB(nxt, kt + 1, 0); STGB(nxt, kt + 1, 1); }
    if (hn) asm volatile("s_waitcnt vmcnt(2)" ::: "memory");
    else    asm volatile("s_waitcnt vmcnt(0)" ::: "memory");
    __builtin_amdgcn_s_barrier();
    asm volatile("" ::: "memory");
    bf16x8 bF[4][2];
#pragma unroll
    for (int jn = 0; jn < 4; ++jn) {
      const int rowb = wn * 64 + jn * 16 + r;
#pragma unroll
      for (int ks = 0; ks < 2; ++ks) {
        const int j = (ks * 4 + kq) ^ (r & 7);
        bF[jn][ks] = *(const bf16x8*)&pB[rowb * 64 + j * 8];
      }
    }
    QUAD(0);
    // ---------------- phase 1 ----------------
    if (hn) { STGB(nxt, kt + 1, 2); STGB(nxt, kt + 1, 3); }
    QUAD(1);
    // pre-read phase-2 fragments (As[cur] published at P0 barrier -> legal)
    bf16x8 aFn[2][2];
#pragma unroll
    for (int ii = 0; ii < 2; ++ii) {
      const int rowa = wm * 128 + (4 + ii) * 16 + r;
#pragma unroll
      for (int ks = 0; ks < 2; ++ks) {
        const int j = (ks * 4 + kq) ^ (r & 7);
        aFn[ii][ks] = *(const bf16x8*)&pA[rowa * 64 + j * 8];
      }
    }
    // ---------------- phase 2 (WAR spacer) ----------------
    if (hn) { STGA(nxt, kt + 1, 0); STGA(nxt, kt + 1, 2); }
    asm volatile("" ::: "memory");
    __builtin_amdgcn_s_barrier();
    __builtin_amdgcn_s_setprio(1);
#pragma unroll
    for (int ii = 0; ii < 2; ++ii)
#pragma unroll
      for (int jn = 0; jn < 4; ++jn)
#pragma unroll
        for (int ks = 0; ks < 2; ++ks)
          acc[4 + ii][jn] = __builtin_amdgcn_mfma_f32_16x16x32_bf16(
              aFn[ii][ks], bF[jn][ks], acc[4 + ii][jn], 0, 0, 0);
    __builtin_amdgcn_s_setprio(0);
    // ---------------- phase 3 ----------------
    if (hn) { STGA(nxt, kt + 1, 1); STGA(nxt, kt + 1, 3); }
    QUAD(3);
  }
#undef STGA
#undef STGB
#undef QUAD

  // ---- epilogue via LDS: swizzled scatter, then coalesced 16B stores ----
  asm volatile("s_waitcnt lgkmcnt(0) vmcnt(0)" ::: "memory");
  __builtin_amdgcn_s_barrier();                   // all waves done with stage LDS

  const int q4 = (l >> 4) * 4;
  float bvj[4];
#pragma unroll
  for (int jn = 0; jn < 4; ++jn) {
    const int col = wn * 64 + jn * 16 + r;
    bvj[jn] = bias ? bias[bn * 256 + col] : 0.f;
  }
#pragma unroll
  for (int i = 0; i < 8; ++i) {
#pragma unroll
    for (int jn = 0; jn < 4; ++jn) {
      const int col = wn * 64 + jn * 16 + r;
      const int chunk = col >> 3;
#pragma unroll
      for (int q = 0; q < 4; ++q) {
        const int rowl = wm * 128 + i * 16 + q4 + q;
        const int pch = chunk ^ (rowl & 7);
        smem[rowl * 256 + pch * 8 + (col & 7)] = f2bf(acc[i][jn][q] + bvj[jn]);
      }
    }
  }
  __builtin_amdgcn_s_barrier();

  const int rrow0 = t >> 5;                       // 0..15
  const int rch = t & 31;                         // logical 16B chunk
#pragma unroll
  for (int p = 0; p < 16; ++p) {
    const int rowl = p * 16 + rrow0;
    const int pch = rch ^ (rowl & 7);
    u16x8 vv = *(const u16x8*)&smem[rowl * 256 + pch * 8];
    const size_t grow = (size_t)(bm * 256 + rowl);
    *(u16x8*)&C[grow * N + bn * 256 + rch * 8] = vv;
  }
}

// ---------------------------------------------------------------------------
// Scan kernels. lin[row, 2048] (bf16): [theta | retain_logit | inp_r | inp_i]
// cum_mag as running product (== exp(cumsum(log(clip(rt,1e-6)))) within fp32
// noise); the 1e-8 clip on the inverse is preserved exactly.
// ---------------------------------------------------------------------------
__global__ __launch_bounds__(256) void scan_k1(const ushort* __restrict__ lin,
                                               float4* __restrict__ agg) {
  int bd = blockIdx.x * 256 + threadIdx.x;    // 0..2047  (b*512 + d)
  int c  = blockIdx.y;                         // 0..127
  int b  = bd >> 9, d = bd & 511;
  const ushort* base = lin + ((size_t)b * 4096 + (size_t)c * 32) * 2048;
  float cth = 0.f, cbr = 0.f, cbi = 0.f;
  float cm = 1.f, cs = 1.f, sn = 0.f;
#pragma unroll 4
  for (int t = 0; t < 32; ++t) {
    const ushort* row = base + (size_t)t * 2048;
    float th = bf2f(row[d]);
    float z  = bf2f(row[512 + d]);
    float ir = bf2f(row[1024 + d]);
    float ii = bf2f(row[1536 + d]);
    float rt = __fdividef(1.f, 1.f + __expf(-z));
    cm *= fmaxf(rt, 1e-6f);
    cth += th;
    float s_, c_;
    __sincosf(cth, &s_, &c_);
    float im = __fdividef(1.f, fmaxf(cm, 1e-8f));
    float invr = im * c_, invi = -im * s_;
    float drive = 1.f - rt;
    float br_ = drive * ir, bi_ = drive * ii;
    cbr += invr * br_ - invi * bi_;
    cbi += invr * bi_ + invi * br_;
    cs = c_; sn = s_;
  }
  agg[(size_t)c * 2048 + bd] = make_float4(cm * cs, cm * sn, cbr, cbi);
}

__global__ __launch_bounds__(256) void scan_k2(const float4* __restrict__ agg,
                                               float2* __restrict__ h0) {
  int bd = blockIdx.x * 256 + threadIdx.x;    // 2048 threads
  float hr = 0.f, hi = 0.f;
  for (int cg = 0; cg < 16; ++cg) {
    float4 a[8];
#pragma unroll
    for (int u = 0; u < 8; ++u) a[u] = agg[(size_t)(cg * 8 + u) * 2048 + bd];
#pragma unroll
    for (int u = 0; u < 8; ++u) {
      h0[(size_t)(cg * 8 + u) * 2048 + bd] = make_float2(hr, hi);
      float tr = hr + a[u].z, ti = hi + a[u].w;
      hr = a[u].x * tr - a[u].y * ti;
      hi = a[u].x * ti + a[u].y * tr;
    }
  }
}

__global__ __launch_bounds__(256) void scan_k3(const ushort* __restrict__ lin,
                                               const float2* __restrict__ h0,
                                               ushort* __restrict__ outb) {
  int bd = blockIdx.x * 256 + threadIdx.x;
  int c  = blockIdx.y;
  int b  = bd >> 9, d = bd & 511;
  const ushort* base = lin + ((size_t)b * 4096 + (size_t)c * 32) * 2048;
  float2 h = h0[(size_t)c * 2048 + bd];
  float cth = 0.f, cbr = 0.f, cbi = 0.f, cm = 1.f;
#pragma unroll 4
  for (int t = 0; t < 32; ++t) {
    const ushort* row = base + (size_t)t * 2048;
    float th = bf2f(row[d]);
    float z  = bf2f(row[512 + d]);
    float ir = bf2f(row[1024 + d]);
    float ii = bf2f(row[1536 + d]);
    float rt = __fdividef(1.f, 1.f + __expf(-z));
    cm *= fmaxf(rt, 1e-6f);
    cth += th;
    float s_, c_;
    __sincosf(cth, &s_, &c_);
    float im = __fdividef(1.f, fmaxf(cm, 1e-8f));
    float invr = im * c_, invi = -im * s_;
    float drive = 1.f - rt;
    float br_ = drive * ir, bi_ = drive * ii;
    cbr += invr * br_ - invi * bi_;
    cbi += invr * bi_ + invi * br_;
    float ar = cm * c_, ai = cm * s_;
    float tr = h.x + cbr, ti = h.y + cbi;
    float orr = ar * tr - ai * ti;
    float oii = ar * ti + ai * tr;
    size_t rowo = ((size_t)b * 4096 + (size_t)c * 32 + t) * 1024;
    outb[rowo + d] = f2bf(orr);
    outb[rowo + 512 + d] = f2bf(oii);
  }
}

// ---------------------------------------------------------------------------
// LayerNorm, one WAVE per row (4 rows/block, no block barrier).
// Lane covers 4 elems in each of 4 row-quarters -> every load/store coalesced.
// y = yb + xb (residual fused).
// ---------------------------------------------------------------------------
__global__ __launch_bounds__(256) void ln_k(const ushort* __restrict__ yb,
                                            const ushort* __restrict__ xb,
                                            const float* __restrict__ gamma,
                                            const float* __restrict__ beta,
                                            float* __restrict__ out) {
  const int lane = threadIdx.x & 63;
  const size_t row = (size_t)blockIdx.x * 4 + (threadIdx.x >> 6);
  const ushort* yr = yb + row * 1024;
  const ushort* xr = xb + row * 1024;
  float v[4][4];
  float s = 0.f, s2 = 0.f;
#pragma unroll
  for (int q = 0; q < 4; ++q) {
    ushort4 uy = *(const ushort4*)(yr + q * 256 + lane * 4);
    ushort4 ux = *(const ushort4*)(xr + q * 256 + lane * 4);
    v[q][0] = bf2f(uy.x) + bf2f(ux.x);
    v[q][1] = bf2f(uy.y) + bf2f(ux.y);
    v[q][2] = bf2f(uy.z) + bf2f(ux.z);
    v[q][3] = bf2f(uy.w) + bf2f(ux.w);
#pragma unroll
    for (int j = 0; j < 4; ++j) { s += v[q][j]; s2 += v[q][j] * v[q][j]; }
  }
#pragma unroll
  for (int off = 32; off > 0; off >>= 1) {
    s  += __shfl_xor(s, off);
    s2 += __shfl_xor(s2, off);
  }
  const float mu = s * (1.f / 1024.f);
  const float rstd = rsqrtf(s2 * (1.f / 1024.f) - mu * mu + 1e-5f);
#pragma unroll
  for (int q = 0; q < 4; ++q) {
    float4 gv = *(const float4*)(gamma + q * 256 + lane * 4);
    float4 bv = *(const float4*)(beta + q * 256 + lane * 4);
    float4 o;
    o.x = (v[q][0] - mu) * rstd * gv.x + bv.x;
    o.y = (v[q][1] - mu) * rstd * gv.y + bv.y;
    o.z = (v[q][2] - mu) * rstd * gv.z + bv.z;
    o.w = (v[q][3] - mu) * rstd * gv.w + bv.w;
    *(float4*)(out + row * 1024 + q * 256 + lane * 4) = o;
  }
}

// ---------------------------------------------------------------------------
extern "C" void kernel_launch(void* const* d_in, const int* in_sizes, int n_in,
                              void* d_out, int out_size, void* d_ws, size_t ws_size,
                              hipStream_t stream) {
  (void)in_sizes; (void)n_in; (void)out_size; (void)ws_size;
  const float* x  = (const float*)d_in[0];
  const float* Wt = (const float*)d_in[1];
  const float* bt = (const float*)d_in[2];
  const float* Wr = (const float*)d_in[3];
  const float* br = (const float*)d_in[4];
  const float* Wi = (const float*)d_in[5];
  const float* bi = (const float*)d_in[6];
  const float* Wo = (const float*)d_in[7];
  const float* bo = (const float*)d_in[8];
  const float* gamma = (const float*)d_in[9];
  const float* beta  = (const float*)d_in[10];

  char* ws = (char*)d_ws;
  ushort* wcat_t = (ushort*)(ws);                      //  4 MiB: [2048][1024] bf16
  ushort* wo_t   = (ushort*)(ws + ((size_t)4  << 20)); //  2 MiB: [1024][1024] bf16
  float*  bcat   = (float*) (ws + ((size_t)6  << 20)); //  8 KiB
  float4* agg    = (float4*)(ws + ((size_t)8  << 20)); //  4 MiB: [128][2048]
  float2* h0     = (float2*)(ws + ((size_t)12 << 20)); //  2 MiB: [128][2048]
  ushort* xb     = (ushort*)(ws + ((size_t)16 << 20)); // 32 MiB: x bf16 (alive thru ln_k)
  ushort* outb   = (ushort*)(ws + ((size_t)48 << 20)); // 32 MiB: scan out bf16
  ushort* linb   = (ushort*)(ws + ((size_t)80 << 20)); // 64 MiB: lin bf16
  ushort* yb     = (ushort*)(ws + ((size_t)80 << 20)); // 32 MiB: y bf16 (overlays dead linb)

  // weight prep (fused) + bias + x conversion
  tconv_all<<<dim3(32, 32, 4), dim3(32, 8), 0, stream>>>(Wt, Wr, Wi, Wo, wcat_t, wo_t);
  pack_bias<<<8, 256, 0, stream>>>(bt, br, bi, bcat);
  xconv<<<16384, 256, 0, stream>>>((const float4*)x, xb, 4194304);

  // lin(bf16) = x @ [Wt|Wr|Wi] + [bt|br|bi]   (M=16384 N=2048 K=1024, 512 blocks)
  gemm256<<<512, 512, 0, stream>>>(xb, wcat_t, linb, bcat, 16384, 2048, 1024, 8);

  // chunked complex scan
  scan_k1<<<dim3(8, 128), 256, 0, stream>>>(linb, agg);
  scan_k2<<<8, 256, 0, stream>>>(agg, h0);
  scan_k3<<<dim3(8, 128), 256, 0, stream>>>(linb, h0, outb);

  // yb(bf16) = out @ Wo + bo   (M=16384 N=1024 K=1024, 256 blocks, 1/CU)
  gemm256<<<256, 512, 0, stream>>>(outb, wo_t, yb, bo, 16384, 1024, 1024, 4);

  // layernorm(yb + xb) -> d_out   (one wave per row)
  ln_k<<<4096, 256, 0, stream>>>(yb, xb, gamma, beta, (float*)d_out);
}

// Round 12
// 198.595 us; speedup vs baseline: 1.1352x; 1.0037x over previous
//
#include <hip/hip_runtime.h>
#include <cstdint>

// ---------------------------------------------------------------------------
// RotationScan: theta/retain/inp GEMM -> chunked complex scan -> out GEMM -> LN
// B=4 T=4096 D=1024 SD=512 CHUNK=32
// r12 = r11 + xconv deleted: GEMM1 reg-stages A from f32 (load->cvt->ds_write),
// ln_k reads x f32 directly. GEMM2 keeps the r11 gload_lds path (template).
// ---------------------------------------------------------------------------

typedef __bf16 bf16x8 __attribute__((ext_vector_type(8)));
typedef float  f32x4  __attribute__((ext_vector_type(4)));
typedef ushort u16x8  __attribute__((ext_vector_type(8)));

#define AS1 __attribute__((address_space(1)))
#define AS3 __attribute__((address_space(3)))

__device__ __forceinline__ void gload16(const void* g, void* l) {
  __builtin_amdgcn_global_load_lds((const AS1 void*)g, (AS3 void*)l, 16, 0, 0);
}

__device__ __forceinline__ ushort f2bf(float f) {
  union { float f; uint32_t u; } v; v.f = f;
  uint32_t u = v.u;
  uint32_t r = u + 0x7FFFu + ((u >> 16) & 1u);   // RNE
  return (ushort)(r >> 16);
}
__device__ __forceinline__ float bf2f(ushort u) {
  union { uint32_t x; float f; } v; v.x = (uint32_t)u << 16; return v.f;
}
__device__ __forceinline__ u16x8 cvt8(float4 a, float4 b) {
  u16x8 o;
  o[0] = f2bf(a.x); o[1] = f2bf(a.y); o[2] = f2bf(a.z); o[3] = f2bf(a.w);
  o[4] = f2bf(b.x); o[5] = f2bf(b.y); o[6] = f2bf(b.z); o[7] = f2bf(b.w);
  return o;
}

// ---------------------------------------------------------------------------
// Fused transpose + f32->bf16 for all 4 weights (one launch).
// ---------------------------------------------------------------------------
__global__ __launch_bounds__(256) void tconv_all(const float* __restrict__ Wt,
                                                 const float* __restrict__ Wr,
                                                 const float* __restrict__ Wi,
                                                 const float* __restrict__ Wo,
                                                 ushort* __restrict__ wcat,
                                                 ushort* __restrict__ wot) {
  const int z = blockIdx.z;
  if (z < 2 && blockIdx.x >= 16) return;          // C=512 weights: 16 col-blocks
  const float* src = (z == 0) ? Wt : (z == 1) ? Wr : (z == 2) ? Wi : Wo;
  const int C = (z < 2) ? 512 : 1024;
  const int row_off = (z == 0) ? 0 : (z == 1) ? 512 : (z == 2) ? 1024 : 0;
  ushort* dst = (z == 3) ? wot : wcat;

  __shared__ float tile[32][33];
  int tx = threadIdx.x, ty = threadIdx.y;
  int rb = blockIdx.y * 32, cb = blockIdx.x * 32;
#pragma unroll
  for (int yy = 0; yy < 4; ++yy) {
    int r = rb + ty + yy * 8;
    tile[ty + yy * 8][tx] = src[(size_t)r * C + cb + tx];
  }
  __syncthreads();
#pragma unroll
  for (int yy = 0; yy < 4; ++yy) {
    int c = cb + ty + yy * 8;
    dst[(size_t)(row_off + c) * 1024 + rb + tx] = f2bf(tile[tx][ty + yy * 8]);
  }
}

__global__ __launch_bounds__(256) void pack_bias(const float* __restrict__ bt,
                                                 const float* __restrict__ br,
                                                 const float* __restrict__ bi,
                                                 float* __restrict__ bcat) {
  int i = blockIdx.x * 256 + threadIdx.x;          // 0..2047
  bcat[i] = (i < 512) ? bt[i] : (i < 1024 ? br[i - 512] : bi[i - 1024]);
}

// ---------------------------------------------------------------------------
// 256x256 tile, BK=64, 8 waves (2Mx4N), double-buffered 128 KiB LDS.
// 16x16x32 MFMA + chunk^(row&7) swizzle (verified conflict-free).
//
// AF32=false (GEMM2): r11 schedule verbatim — 8 gload_lds/K-tile,
//   P0 wait vmcnt(2) [tail 0], P2 WAR-spacer barrier, QUAD2 pre-read.
// AF32=true (GEMM1): A reg-staged from f32.
//   P0: stage B0,B1(kt+1) via gload_lds + issue 8 A-f32 dwordx4 loads(kt+1);
//       wait vmcnt(10) lgkmcnt(0) [tail vmcnt(0) lgkmcnt(0)] — entry
//       outstanding <=4 (B(kt)); +10 issued -> oldest 4 (B(kt)) drained;
//       lgkmcnt publishes previous tile's A ds_writes; barrier; bF+aF q0; MFMA.
//   P1: stage B2,B3(kt+1); QUAD1; pre-read aF q2.
//   P2: cvt+ds_write A passes 0,1 -> As[nxt] (reads sealed at P0 barrier;
//       A-load RAW enforced by compiler's own vmcnt before first use);
//       clobber+barrier (WAR spacer for Bs[cur]); 16 MFMA on pre-read q2.
//   P3: cvt+ds_write A passes 2,3; QUAD3.
// Epilogue (r7-verified): C-tile -> LDS 16B-chunk XOR swizzle -> coalesced
// u16x8 stores.
// ---------------------------------------------------------------------------
template <bool AF32>
__global__ __launch_bounds__(512, 2) void gemm256(const void* __restrict__ Aptr,
                                                  const ushort* __restrict__ Bt,
                                                  ushort* __restrict__ C,
                                                  const float* __restrict__ bias,
                                                  int M, int N, int K, int nbn) {
  __shared__ alignas(16) ushort smem[65536];      // stage 128KB == C-tile 128KB
  ushort* const As0 = smem;                       // As(buf) = As0 + buf*256*64
  ushort* const Bs0 = smem + 2 * 256 * 64;        // Bs(buf) = Bs0 + buf*256*64

  const int cpx = gridDim.x >> 3;
  const int wg = ((int)blockIdx.x & 7) * cpx + ((int)blockIdx.x >> 3);
  const int bm = wg / nbn, bn = wg % nbn;

  const int t = threadIdx.x;
  const int l = t & 63, w = t >> 6;
  const int wm = w >> 2, wn = w & 3;              // wave grid 2(M) x 4(N)
  const int r = l & 15, kq = l >> 4;

  const size_t a0 = (size_t)bm * 256 * K;
  const size_t b0 = (size_t)bn * 256 * K;

  const int srow = t >> 3;                        // 0..63
  const int sslot = (t & 7) ^ (srow & 7);
  const ushort* gA16 = (const ushort*)Aptr + a0 + (size_t)srow * K + sslot * 8;
  const float*  gAf  = (const float*)Aptr + a0 + (size_t)srow * K + sslot * 8;
  const ushort* gB = Bt + b0 + (size_t)srow * K + sslot * 8;
  const int lboff = w * 1024 + l * 16;            // LDS byte offset in a pass

  f32x4 acc[8][4] = {};
  const int NKT = K >> 6;
  float4 areg[4][2];                              // AF32: in-flight A f32 tile

#define STGA(buf, kt, u) \
  gload16(gA16 + (size_t)((u) * 64) * K + (size_t)(kt) * 64, \
          (char*)(As0 + (buf) * 256 * 64) + (u) * 8192 + lboff)
#define STGB(buf, kt, u) \
  gload16(gB + (size_t)((u) * 64) * K + (size_t)(kt) * 64, \
          (char*)(Bs0 + (buf) * 256 * 64) + (u) * 8192 + lboff)
#define ALOAD(kt, u) \
  do { const float* gs_ = gAf + (size_t)((u) * 64) * K + (size_t)(kt) * 64; \
       areg[u][0] = *(const float4*)gs_; areg[u][1] = *(const float4*)(gs_ + 4); } while (0)
#define AWRITE(buf, u) \
  *(u16x8*)((char*)(As0 + (buf) * 256 * 64) + (u) * 8192 + lboff) = cvt8(areg[u][0], areg[u][1])

#define QUAD(ph)                                                               \
  do {                                                                         \
    _Pragma("unroll")                                                          \
    for (int ii = 0; ii < 2; ++ii) {                                           \
      bf16x8 aF[2];                                                            \
      const int rowa = wm * 128 + ((ph) * 2 + ii) * 16 + r;                    \
      _Pragma("unroll")                                                        \
      for (int ks = 0; ks < 2; ++ks) {                                         \
        const int j = (ks * 4 + kq) ^ (r & 7);                                 \
        aF[ks] = *(const bf16x8*)&pA[rowa * 64 + j * 8];                       \
      }                                                                        \
      __builtin_amdgcn_s_setprio(1);                                           \
      _Pragma("unroll")                                                        \
      for (int jn = 0; jn < 4; ++jn)                                           \
        _Pragma("unroll")                                                      \
        for (int ks = 0; ks < 2; ++ks)                                         \
          acc[(ph) * 2 + ii][jn] = __builtin_amdgcn_mfma_f32_16x16x32_bf16(    \
              aF[ks], bF[jn][ks], acc[(ph) * 2 + ii][jn], 0, 0, 0);            \
      __builtin_amdgcn_s_setprio(0);                                           \
    }                                                                          \
  } while (0)

  // prologue: B(0) staged; A(0) loaded+converted+written (compiler waits loads)
  STGB(0, 0, 0); STGB(0, 0, 1); STGB(0, 0, 2); STGB(0, 0, 3);
  if constexpr (AF32) {
#pragma unroll
    for (int u = 0; u < 4; ++u) ALOAD(0, u);
#pragma unroll
    for (int u = 0; u < 4; ++u) AWRITE(0, u);
  } else {
    STGA(0, 0, 0); STGA(0, 0, 2); STGA(0, 0, 1); STGA(0, 0, 3);
  }

  for (int kt = 0; kt < NKT; ++kt) {
    const int cur = kt & 1, nxt = cur ^ 1;
    const bool hn = (kt + 1 < NKT);
    const ushort* pA = As0 + cur * 256 * 64;
    const ushort* pB = Bs0 + cur * 256 * 64;

    // ---------------- phase 0 (publish) ----------------
    if (hn) { STGB(nxt, kt + 1, 0); STGB(nxt, kt + 1, 1); }
    if constexpr (AF32) {
      if (hn) {
#pragma unroll
        for (int u = 0; u < 4; ++u) ALOAD(kt + 1, u);
        asm volatile("s_waitcnt vmcnt(10) lgkmcnt(0)" ::: "memory");
      } else {
        asm volatile("s_waitcnt vmcnt(0) lgkmcnt(0)" ::: "memory");
      }
    } else {
      if (hn) asm volatile("s_waitcnt vmcnt(2)" ::: "memory");
      else    asm volatile("s_waitcnt vmcnt(0)" ::: "memory");
    }
    __builtin_amdgcn_s_barrier();
    asm volatile("" ::: "memory");
    bf16x8 bF[4][2];
#pragma unroll
    for (int jn = 0; jn < 4; ++jn) {
      const int rowb = wn * 64 + jn * 16 + r;
#pragma unroll
      for (int ks = 0; ks < 2; ++ks) {
        const int j = (ks * 4 + kq) ^ (r & 7);
        bF[jn][ks] = *(const bf16x8*)&pB[rowb * 64 + j * 8];
      }
    }
    QUAD(0);
    // ---------------- phase 1 ----------------
    if (hn) { STGB(nxt, kt + 1, 2); STGB(nxt, kt + 1, 3); }
    QUAD(1);
    // pre-read phase-2 fragments (As[cur] published at P0 barrier -> legal)
    bf16x8 aFn[2][2];
#pragma unroll
    for (int ii = 0; ii < 2; ++ii) {
      const int rowa = wm * 128 + (4 + ii) * 16 + r;
#pragma unroll
      for (int ks = 0; ks < 2; ++ks) {
        const int j = (ks * 4 + kq) ^ (r & 7);
        aFn[ii][ks] = *(const bf16x8*)&pA[rowa * 64 + j * 8];
      }
    }
    // ---------------- phase 2 (WAR spacer) ----------------
    if (hn) {
      if constexpr (AF32) { AWRITE(nxt, 0); AWRITE(nxt, 1); }
      else                { STGA(nxt, kt + 1, 0); STGA(nxt, kt + 1, 2); }
    }
    asm volatile("" ::: "memory");
    __builtin_amdgcn_s_barrier();
    __builtin_amdgcn_s_setprio(1);
#pragma unroll
    for (int ii = 0; ii < 2; ++ii)
#pragma unroll
      for (int jn = 0; jn < 4; ++jn)
#pragma unroll
        for (int ks = 0; ks < 2; ++ks)
          acc[4 + ii][jn] = __builtin_amdgcn_mfma_f32_16x16x32_bf16(
              aFn[ii][ks], bF[jn][ks], acc[4 + ii][jn], 0, 0, 0);
    __builtin_amdgcn_s_setprio(0);
    // ---------------- phase 3 ----------------
    if (hn) {
      if constexpr (AF32) { AWRITE(nxt, 2); AWRITE(nxt, 3); }
      else                { STGA(nxt, kt + 1, 1); STGA(nxt, kt + 1, 3); }
    }
    QUAD(3);
  }
#undef STGA
#undef STGB
#undef ALOAD
#undef AWRITE
#undef QUAD

  // ---- epilogue via LDS: swizzled scatter, then coalesced 16B stores ----
  asm volatile("s_waitcnt lgkmcnt(0) vmcnt(0)" ::: "memory");
  __builtin_amdgcn_s_barrier();                   // all waves done with stage LDS

  const int q4 = (l >> 4) * 4;
  float bvj[4];
#pragma unroll
  for (int jn = 0; jn < 4; ++jn) {
    const int col = wn * 64 + jn * 16 + r;
    bvj[jn] = bias ? bias[bn * 256 + col] : 0.f;
  }
#pragma unroll
  for (int i = 0; i < 8; ++i) {
#pragma unroll
    for (int jn = 0; jn < 4; ++jn) {
      const int col = wn * 64 + jn * 16 + r;
      const int chunk = col >> 3;
#pragma unroll
      for (int q = 0; q < 4; ++q) {
        const int rowl = wm * 128 + i * 16 + q4 + q;
        const int pch = chunk ^ (rowl & 7);
        smem[rowl * 256 + pch * 8 + (col & 7)] = f2bf(acc[i][jn][q] + bvj[jn]);
      }
    }
  }
  __builtin_amdgcn_s_barrier();

  const int rrow0 = t >> 5;                       // 0..15
  const int rch = t & 31;                         // logical 16B chunk
#pragma unroll
  for (int p = 0; p < 16; ++p) {
    const int rowl = p * 16 + rrow0;
    const int pch = rch ^ (rowl & 7);
    u16x8 vv = *(const u16x8*)&smem[rowl * 256 + pch * 8];
    const size_t grow = (size_t)(bm * 256 + rowl);
    *(u16x8*)&C[grow * N + bn * 256 + rch * 8] = vv;
  }
}

// ---------------------------------------------------------------------------
// Scan kernels. lin[row, 2048] (bf16): [theta | retain_logit | inp_r | inp_i]
// cum_mag as running product (== exp(cumsum(log(clip(rt,1e-6)))) within fp32
// noise); the 1e-8 clip on the inverse is preserved exactly.
// ---------------------------------------------------------------------------
__global__ __launch_bounds__(256) void scan_k1(const ushort* __restrict__ lin,
                                               float4* __restrict__ agg) {
  int bd = blockIdx.x * 256 + threadIdx.x;    // 0..2047  (b*512 + d)
  int c  = blockIdx.y;                         // 0..127
  int b  = bd >> 9, d = bd & 511;
  const ushort* base = lin + ((size_t)b * 4096 + (size_t)c * 32) * 2048;
  float cth = 0.f, cbr = 0.f, cbi = 0.f;
  float cm = 1.f, cs = 1.f, sn = 0.f;
#pragma unroll 4
  for (int t = 0; t < 32; ++t) {
    const ushort* row = base + (size_t)t * 2048;
    float th = bf2f(row[d]);
    float z  = bf2f(row[512 + d]);
    float ir = bf2f(row[1024 + d]);
    float ii = bf2f(row[1536 + d]);
    float rt = __fdividef(1.f, 1.f + __expf(-z));
    cm *= fmaxf(rt, 1e-6f);
    cth += th;
    float s_, c_;
    __sincosf(cth, &s_, &c_);
    float im = __fdividef(1.f, fmaxf(cm, 1e-8f));
    float invr = im * c_, invi = -im * s_;
    float drive = 1.f - rt;
    float br_ = drive * ir, bi_ = drive * ii;
    cbr += invr * br_ - invi * bi_;
    cbi += invr * bi_ + invi * br_;
    cs = c_; sn = s_;
  }
  agg[(size_t)c * 2048 + bd] = make_float4(cm * cs, cm * sn, cbr, cbi);
}

__global__ __launch_bounds__(256) void scan_k2(const float4* __restrict__ agg,
                                               float2* __restrict__ h0) {
  int bd = blockIdx.x * 256 + threadIdx.x;    // 2048 threads
  float hr = 0.f, hi = 0.f;
  for (int cg = 0; cg < 16; ++cg) {
    float4 a[8];
#pragma unroll
    for (int u = 0; u < 8; ++u) a[u] = agg[(size_t)(cg * 8 + u) * 2048 + bd];
#pragma unroll
    for (int u = 0; u < 8; ++u) {
      h0[(size_t)(cg * 8 + u) * 2048 + bd] = make_float2(hr, hi);
      float tr = hr + a[u].z, ti = hi + a[u].w;
      hr = a[u].x * tr - a[u].y * ti;
      hi = a[u].x * ti + a[u].y * tr;
    }
  }
}

__global__ __launch_bounds__(256) void scan_k3(const ushort* __restrict__ lin,
                                               const float2* __restrict__ h0,
                                               ushort* __restrict__ outb) {
  int bd = blockIdx.x * 256 + threadIdx.x;
  int c  = blockIdx.y;
  int b  = bd >> 9, d = bd & 511;
  const ushort* base = lin + ((size_t)b * 4096 + (size_t)c * 32) * 2048;
  float2 h = h0[(size_t)c * 2048 + bd];
  float cth = 0.f, cbr = 0.f, cbi = 0.f, cm = 1.f;
#pragma unroll 4
  for (int t = 0; t < 32; ++t) {
    const ushort* row = base + (size_t)t * 2048;
    float th = bf2f(row[d]);
    float z  = bf2f(row[512 + d]);
    float ir = bf2f(row[1024 + d]);
    float ii = bf2f(row[1536 + d]);
    float rt = __fdividef(1.f, 1.f + __expf(-z));
    cm *= fmaxf(rt, 1e-6f);
    cth += th;
    float s_, c_;
    __sincosf(cth, &s_, &c_);
    float im = __fdividef(1.f, fmaxf(cm, 1e-8f));
    float invr = im * c_, invi = -im * s_;
    float drive = 1.f - rt;
    float br_ = drive * ir, bi_ = drive * ii;
    cbr += invr * br_ - invi * bi_;
    cbi += invr * bi_ + invi * br_;
    float ar = cm * c_, ai = cm * s_;
    float tr = h.x + cbr, ti = h.y + cbi;
    float orr = ar * tr - ai * ti;
    float oii = ar * ti + ai * tr;
    size_t rowo = ((size_t)b * 4096 + (size_t)c * 32 + t) * 1024;
    outb[rowo + d] = f2bf(orr);
    outb[rowo + 512 + d] = f2bf(oii);
  }
}

// ---------------------------------------------------------------------------
// LayerNorm, one WAVE per row (4 rows/block). y = yb(bf16) + x(f32 residual).
// ---------------------------------------------------------------------------
__global__ __launch_bounds__(256) void ln_k(const ushort* __restrict__ yb,
                                            const float* __restrict__ x,
                                            const float* __restrict__ gamma,
                                            const float* __restrict__ beta,
                                            float* __restrict__ out) {
  const int lane = threadIdx.x & 63;
  const size_t row = (size_t)blockIdx.x * 4 + (threadIdx.x >> 6);
  const ushort* yr = yb + row * 1024;
  const float* xr = x + row * 1024;
  float v[4][4];
  float s = 0.f, s2 = 0.f;
#pragma unroll
  for (int q = 0; q < 4; ++q) {
    ushort4 uy = *(const ushort4*)(yr + q * 256 + lane * 4);
    float4 fx = *(const float4*)(xr + q * 256 + lane * 4);
    v[q][0] = bf2f(uy.x) + fx.x;
    v[q][1] = bf2f(uy.y) + fx.y;
    v[q][2] = bf2f(uy.z) + fx.z;
    v[q][3] = bf2f(uy.w) + fx.w;
#pragma unroll
    for (int j = 0; j < 4; ++j) { s += v[q][j]; s2 += v[q][j] * v[q][j]; }
  }
#pragma unroll
  for (int off = 32; off > 0; off >>= 1) {
    s  += __shfl_xor(s, off);
    s2 += __shfl_xor(s2, off);
  }
  const float mu = s * (1.f / 1024.f);
  const float rstd = rsqrtf(s2 * (1.f / 1024.f) - mu * mu + 1e-5f);
#pragma unroll
  for (int q = 0; q < 4; ++q) {
    float4 gv = *(const float4*)(gamma + q * 256 + lane * 4);
    float4 bv = *(const float4*)(beta + q * 256 + lane * 4);
    float4 o;
    o.x = (v[q][0] - mu) * rstd * gv.x + bv.x;
    o.y = (v[q][1] - mu) * rstd * gv.y + bv.y;
    o.z = (v[q][2] - mu) * rstd * gv.z + bv.z;
    o.w = (v[q][3] - mu) * rstd * gv.w + bv.w;
    *(float4*)(out + row * 1024 + q * 256 + lane * 4) = o;
  }
}

// ---------------------------------------------------------------------------
extern "C" void kernel_launch(void* const* d_in, const int* in_sizes, int n_in,
                              void* d_out, int out_size, void* d_ws, size_t ws_size,
                              hipStream_t stream) {
  (void)in_sizes; (void)n_in; (void)out_size; (void)ws_size;
  const float* x  = (const float*)d_in[0];
  const float* Wt = (const float*)d_in[1];
  const float* bt = (const float*)d_in[2];
  const float* Wr = (const float*)d_in[3];
  const float* br = (const float*)d_in[4];
  const float* Wi = (const float*)d_in[5];
  const float* bi = (const float*)d_in[6];
  const float* Wo = (const float*)d_in[7];
  const float* bo = (const float*)d_in[8];
  const float* gamma = (const float*)d_in[9];
  const float* beta  = (const float*)d_in[10];

  char* ws = (char*)d_ws;
  ushort* wcat_t = (ushort*)(ws);                      //  4 MiB: [2048][1024] bf16
  ushort* wo_t   = (ushort*)(ws + ((size_t)4  << 20)); //  2 MiB: [1024][1024] bf16
  float*  bcat   = (float*) (ws + ((size_t)6  << 20)); //  8 KiB
  float4* agg    = (float4*)(ws + ((size_t)8  << 20)); //  4 MiB: [128][2048]
  float2* h0     = (float2*)(ws + ((size_t)12 << 20)); //  2 MiB: [128][2048]
  ushort* outb   = (ushort*)(ws + ((size_t)48 << 20)); // 32 MiB: scan out bf16
  ushort* linb   = (ushort*)(ws + ((size_t)80 << 20)); // 64 MiB: lin bf16
  ushort* yb     = (ushort*)(ws + ((size_t)80 << 20)); // 32 MiB: y bf16 (overlays dead linb)

  // weight prep (fused) + bias pack
  tconv_all<<<dim3(32, 32, 4), dim3(32, 8), 0, stream>>>(Wt, Wr, Wi, Wo, wcat_t, wo_t);
  pack_bias<<<8, 256, 0, stream>>>(bt, br, bi, bcat);

  // lin(bf16) = x(f32, converted in-kernel) @ [Wt|Wr|Wi] + [bt|br|bi]
  gemm256<true><<<512, 512, 0, stream>>>(x, wcat_t, linb, bcat, 16384, 2048, 1024, 8);

  // chunked complex scan
  scan_k1<<<dim3(8, 128), 256, 0, stream>>>(linb, agg);
  scan_k2<<<8, 256, 0, stream>>>(agg, h0);
  scan_k3<<<dim3(8, 128), 256, 0, stream>>>(linb, h0, outb);

  // yb(bf16) = out @ Wo + bo   (256 blocks, 1/CU)
  gemm256<false><<<256, 512, 0, stream>>>(outb, wo_t, yb, bo, 16384, 1024, 1024, 4);

  // layernorm(yb + x) -> d_out   (one wave per row, f32 residual)
  ln_k<<<4096, 256, 0, stream>>>(yb, x, gamma, beta, (float*)d_out);
}

// Round 13
// 193.451 us; speedup vs baseline: 1.1654x; 1.0266x over previous
//
#include <hip/hip_runtime.h>
#include <cstdint>

// ---------------------------------------------------------------------------
// RotationScan: theta/retain/inp GEMM -> chunked complex scan -> out GEMM -> LN
// B=4 T=4096 D=1024 SD=512 CHUNK=32
// r13 = r12 + A-f32 prefetch moved one K-tile earlier (issue A(kt+2) loads at
// P2/P3(kt), AWRITE(kt+1) same phases): restores full-tile latency slack that
// r12's same-tile issue lacked (the ~40us regression mechanism).
// ---------------------------------------------------------------------------

typedef __bf16 bf16x8 __attribute__((ext_vector_type(8)));
typedef float  f32x4  __attribute__((ext_vector_type(4)));
typedef ushort u16x8  __attribute__((ext_vector_type(8)));

#define AS1 __attribute__((address_space(1)))
#define AS3 __attribute__((address_space(3)))

__device__ __forceinline__ void gload16(const void* g, void* l) {
  __builtin_amdgcn_global_load_lds((const AS1 void*)g, (AS3 void*)l, 16, 0, 0);
}

__device__ __forceinline__ ushort f2bf(float f) {
  union { float f; uint32_t u; } v; v.f = f;
  uint32_t u = v.u;
  uint32_t r = u + 0x7FFFu + ((u >> 16) & 1u);   // RNE
  return (ushort)(r >> 16);
}
__device__ __forceinline__ float bf2f(ushort u) {
  union { uint32_t x; float f; } v; v.x = (uint32_t)u << 16; return v.f;
}
__device__ __forceinline__ u16x8 cvt8(float4 a, float4 b) {
  u16x8 o;
  o[0] = f2bf(a.x); o[1] = f2bf(a.y); o[2] = f2bf(a.z); o[3] = f2bf(a.w);
  o[4] = f2bf(b.x); o[5] = f2bf(b.y); o[6] = f2bf(b.z); o[7] = f2bf(b.w);
  return o;
}

// ---------------------------------------------------------------------------
// Fused transpose + f32->bf16 for all 4 weights (one launch).
// ---------------------------------------------------------------------------
__global__ __launch_bounds__(256) void tconv_all(const float* __restrict__ Wt,
                                                 const float* __restrict__ Wr,
                                                 const float* __restrict__ Wi,
                                                 const float* __restrict__ Wo,
                                                 ushort* __restrict__ wcat,
                                                 ushort* __restrict__ wot) {
  const int z = blockIdx.z;
  if (z < 2 && blockIdx.x >= 16) return;          // C=512 weights: 16 col-blocks
  const float* src = (z == 0) ? Wt : (z == 1) ? Wr : (z == 2) ? Wi : Wo;
  const int C = (z < 2) ? 512 : 1024;
  const int row_off = (z == 0) ? 0 : (z == 1) ? 512 : (z == 2) ? 1024 : 0;
  ushort* dst = (z == 3) ? wot : wcat;

  __shared__ float tile[32][33];
  int tx = threadIdx.x, ty = threadIdx.y;
  int rb = blockIdx.y * 32, cb = blockIdx.x * 32;
#pragma unroll
  for (int yy = 0; yy < 4; ++yy) {
    int r = rb + ty + yy * 8;
    tile[ty + yy * 8][tx] = src[(size_t)r * C + cb + tx];
  }
  __syncthreads();
#pragma unroll
  for (int yy = 0; yy < 4; ++yy) {
    int c = cb + ty + yy * 8;
    dst[(size_t)(row_off + c) * 1024 + rb + tx] = f2bf(tile[tx][ty + yy * 8]);
  }
}

__global__ __launch_bounds__(256) void pack_bias(const float* __restrict__ bt,
                                                 const float* __restrict__ br,
                                                 const float* __restrict__ bi,
                                                 float* __restrict__ bcat) {
  int i = blockIdx.x * 256 + threadIdx.x;          // 0..2047
  bcat[i] = (i < 512) ? bt[i] : (i < 1024 ? br[i - 512] : bi[i - 1024]);
}

// ---------------------------------------------------------------------------
// 256x256 tile, BK=64, 8 waves (2Mx4N), double-buffered 128 KiB LDS.
// 16x16x32 MFMA + chunk^(row&7) swizzle (verified conflict-free).
//
// AF32=false (GEMM2): r11 schedule verbatim — 8 gload_lds/K-tile,
//   P0 wait vmcnt(2) [tail 0], P2 WAR-spacer barrier, QUAD2 pre-read.
// AF32=true (GEMM1): A reg-staged from f32 with ONE-TILE-DEEP prefetch:
//   P0: stage B0,B1(kt+1); wait vmcnt(10) lgkmcnt(0) [tail vmcnt(0)]:
//       newest 10 = {B0B1(kt+1), A(kt+1) 8 loads from P2/P3(kt-1)} ->
//       B(kt) fully landed; lgkmcnt publishes kt-1's A ds_writes; barrier.
//   P1: stage B2,B3(kt+1); QUAD1; pre-read aF q2.
//   P2: AWRITE(nxt, p0,p1) [consumes A(kt+1) p0p1, 4-phase slack];
//       ALOAD(kt+2, p0,p1) [refills areg after the ds_write reads them];
//       clobber+barrier (WAR spacer); MFMA q2.
//   P3: AWRITE(nxt, p2,p3); ALOAD(kt+2, p2,p3); QUAD3.
// WAR audit unchanged from r11/r12; areg WAR is program-order (ds_write
// reads regs at issue, subsequent load overwrites after).
// Epilogue (r7-verified): C-tile -> LDS 16B-chunk XOR swizzle -> coalesced
// u16x8 stores.
// ---------------------------------------------------------------------------
template <bool AF32>
__global__ __launch_bounds__(512, 2) void gemm256(const void* __restrict__ Aptr,
                                                  const ushort* __restrict__ Bt,
                                                  ushort* __restrict__ C,
                                                  const float* __restrict__ bias,
                                                  int M, int N, int K, int nbn) {
  __shared__ alignas(16) ushort smem[65536];      // stage 128KB == C-tile 128KB
  ushort* const As0 = smem;                       // As(buf) = As0 + buf*256*64
  ushort* const Bs0 = smem + 2 * 256 * 64;        // Bs(buf) = Bs0 + buf*256*64

  const int cpx = gridDim.x >> 3;
  const int wg = ((int)blockIdx.x & 7) * cpx + ((int)blockIdx.x >> 3);
  const int bm = wg / nbn, bn = wg % nbn;

  const int t = threadIdx.x;
  const int l = t & 63, w = t >> 6;
  const int wm = w >> 2, wn = w & 3;              // wave grid 2(M) x 4(N)
  const int r = l & 15, kq = l >> 4;

  const size_t a0 = (size_t)bm * 256 * K;
  const size_t b0 = (size_t)bn * 256 * K;

  const int srow = t >> 3;                        // 0..63
  const int sslot = (t & 7) ^ (srow & 7);
  const ushort* gA16 = (const ushort*)Aptr + a0 + (size_t)srow * K + sslot * 8;
  const float*  gAf  = (const float*)Aptr + a0 + (size_t)srow * K + sslot * 8;
  const ushort* gB = Bt + b0 + (size_t)srow * K + sslot * 8;
  const int lboff = w * 1024 + l * 16;            // LDS byte offset in a pass

  f32x4 acc[8][4] = {};
  const int NKT = K >> 6;
  float4 areg[4][2];                              // AF32: in-flight A f32 tile

#define STGA(buf, kt, u) \
  gload16(gA16 + (size_t)((u) * 64) * K + (size_t)(kt) * 64, \
          (char*)(As0 + (buf) * 256 * 64) + (u) * 8192 + lboff)
#define STGB(buf, kt, u) \
  gload16(gB + (size_t)((u) * 64) * K + (size_t)(kt) * 64, \
          (char*)(Bs0 + (buf) * 256 * 64) + (u) * 8192 + lboff)
#define ALOAD(kt, u) \
  do { const float* gs_ = gAf + (size_t)((u) * 64) * K + (size_t)(kt) * 64; \
       areg[u][0] = *(const float4*)gs_; areg[u][1] = *(const float4*)(gs_ + 4); } while (0)
#define AWRITE(buf, u) \
  *(u16x8*)((char*)(As0 + (buf) * 256 * 64) + (u) * 8192 + lboff) = cvt8(areg[u][0], areg[u][1])

#define QUAD(ph)                                                               \
  do {                                                                         \
    _Pragma("unroll")                                                          \
    for (int ii = 0; ii < 2; ++ii) {                                           \
      bf16x8 aF[2];                                                            \
      const int rowa = wm * 128 + ((ph) * 2 + ii) * 16 + r;                    \
      _Pragma("unroll")                                                        \
      for (int ks = 0; ks < 2; ++ks) {                                         \
        const int j = (ks * 4 + kq) ^ (r & 7);                                 \
        aF[ks] = *(const bf16x8*)&pA[rowa * 64 + j * 8];                       \
      }                                                                        \
      __builtin_amdgcn_s_setprio(1);                                           \
      _Pragma("unroll")                                                        \
      for (int jn = 0; jn < 4; ++jn)                                           \
        _Pragma("unroll")                                                      \
        for (int ks = 0; ks < 2; ++ks)                                         \
          acc[(ph) * 2 + ii][jn] = __builtin_amdgcn_mfma_f32_16x16x32_bf16(    \
              aF[ks], bF[jn][ks], acc[(ph) * 2 + ii][jn], 0, 0, 0);            \
      __builtin_amdgcn_s_setprio(0);                                           \
    }                                                                          \
  } while (0)

  // prologue
  if constexpr (AF32) {
#pragma unroll
    for (int u = 0; u < 4; ++u) ALOAD(0, u);      // A(0) loads (oldest)
    STGB(0, 0, 0); STGB(0, 0, 1); STGB(0, 0, 2); STGB(0, 0, 3);
#pragma unroll
    for (int u = 0; u < 4; ++u) AWRITE(0, u);     // compiler waits A(0) loads
    if (NKT > 1) {
#pragma unroll
      for (int u = 0; u < 4; ++u) ALOAD(1, u);    // prefetch tile 1
    }
  } else {
    STGB(0, 0, 0); STGB(0, 0, 1); STGB(0, 0, 2); STGB(0, 0, 3);
    STGA(0, 0, 0); STGA(0, 0, 2); STGA(0, 0, 1); STGA(0, 0, 3);
  }

  for (int kt = 0; kt < NKT; ++kt) {
    const int cur = kt & 1, nxt = cur ^ 1;
    const bool hn = (kt + 1 < NKT);
    const ushort* pA = As0 + cur * 256 * 64;
    const ushort* pB = Bs0 + cur * 256 * 64;

    // ---------------- phase 0 (publish) ----------------
    if (hn) { STGB(nxt, kt + 1, 0); STGB(nxt, kt + 1, 1); }
    if constexpr (AF32) {
      if (hn) asm volatile("s_waitcnt vmcnt(10) lgkmcnt(0)" ::: "memory");
      else    asm volatile("s_waitcnt vmcnt(0) lgkmcnt(0)" ::: "memory");
    } else {
      if (hn) asm volatile("s_waitcnt vmcnt(2)" ::: "memory");
      else    asm volatile("s_waitcnt vmcnt(0)" ::: "memory");
    }
    __builtin_amdgcn_s_barrier();
    asm volatile("" ::: "memory");
    bf16x8 bF[4][2];
#pragma unroll
    for (int jn = 0; jn < 4; ++jn) {
      const int rowb = wn * 64 + jn * 16 + r;
#pragma unroll
      for (int ks = 0; ks < 2; ++ks) {
        const int j = (ks * 4 + kq) ^ (r & 7);
        bF[jn][ks] = *(const bf16x8*)&pB[rowb * 64 + j * 8];
      }
    }
    QUAD(0);
    // ---------------- phase 1 ----------------
    if (hn) { STGB(nxt, kt + 1, 2); STGB(nxt, kt + 1, 3); }
    QUAD(1);
    // pre-read phase-2 fragments (As[cur] published at P0 barrier -> legal)
    bf16x8 aFn[2][2];
#pragma unroll
    for (int ii = 0; ii < 2; ++ii) {
      const int rowa = wm * 128 + (4 + ii) * 16 + r;
#pragma unroll
      for (int ks = 0; ks < 2; ++ks) {
        const int j = (ks * 4 + kq) ^ (r & 7);
        aFn[ii][ks] = *(const bf16x8*)&pA[rowa * 64 + j * 8];
      }
    }
    // ---------------- phase 2 (WAR spacer) ----------------
    if constexpr (AF32) {
      if (hn) { AWRITE(nxt, 0); AWRITE(nxt, 1); }        // consume A(kt+1) p0,p1
      if (kt + 2 < NKT) { ALOAD(kt + 2, 0); ALOAD(kt + 2, 1); }  // refill
    } else {
      if (hn) { STGA(nxt, kt + 1, 0); STGA(nxt, kt + 1, 2); }
    }
    asm volatile("" ::: "memory");
    __builtin_amdgcn_s_barrier();
    __builtin_amdgcn_s_setprio(1);
#pragma unroll
    for (int ii = 0; ii < 2; ++ii)
#pragma unroll
      for (int jn = 0; jn < 4; ++jn)
#pragma unroll
        for (int ks = 0; ks < 2; ++ks)
          acc[4 + ii][jn] = __builtin_amdgcn_mfma_f32_16x16x32_bf16(
              aFn[ii][ks], bF[jn][ks], acc[4 + ii][jn], 0, 0, 0);
    __builtin_amdgcn_s_setprio(0);
    // ---------------- phase 3 ----------------
    if constexpr (AF32) {
      if (hn) { AWRITE(nxt, 2); AWRITE(nxt, 3); }
      if (kt + 2 < NKT) { ALOAD(kt + 2, 2); ALOAD(kt + 2, 3); }
    } else {
      if (hn) { STGA(nxt, kt + 1, 1); STGA(nxt, kt + 1, 3); }
    }
    QUAD(3);
  }
#undef STGA
#undef STGB
#undef ALOAD
#undef AWRITE
#undef QUAD

  // ---- epilogue via LDS: swizzled scatter, then coalesced 16B stores ----
  asm volatile("s_waitcnt lgkmcnt(0) vmcnt(0)" ::: "memory");
  __builtin_amdgcn_s_barrier();                   // all waves done with stage LDS

  const int q4 = (l >> 4) * 4;
  float bvj[4];
#pragma unroll
  for (int jn = 0; jn < 4; ++jn) {
    const int col = wn * 64 + jn * 16 + r;
    bvj[jn] = bias ? bias[bn * 256 + col] : 0.f;
  }
#pragma unroll
  for (int i = 0; i < 8; ++i) {
#pragma unroll
    for (int jn = 0; jn < 4; ++jn) {
      const int col = wn * 64 + jn * 16 + r;
      const int chunk = col >> 3;
#pragma unroll
      for (int q = 0; q < 4; ++q) {
        const int rowl = wm * 128 + i * 16 + q4 + q;
        const int pch = chunk ^ (rowl & 7);
        smem[rowl * 256 + pch * 8 + (col & 7)] = f2bf(acc[i][jn][q] + bvj[jn]);
      }
    }
  }
  __builtin_amdgcn_s_barrier();

  const int rrow0 = t >> 5;                       // 0..15
  const int rch = t & 31;                         // logical 16B chunk
#pragma unroll
  for (int p = 0; p < 16; ++p) {
    const int rowl = p * 16 + rrow0;
    const int pch = rch ^ (rowl & 7);
    u16x8 vv = *(const u16x8*)&smem[rowl * 256 + pch * 8];
    const size_t grow = (size_t)(bm * 256 + rowl);
    *(u16x8*)&C[grow * N + bn * 256 + rch * 8] = vv;
  }
}

// ---------------------------------------------------------------------------
// Scan kernels. lin[row, 2048] (bf16): [theta | retain_logit | inp_r | inp_i]
// cum_mag as running product (== exp(cumsum(log(clip(rt,1e-6)))) within fp32
// noise); the 1e-8 clip on the inverse is preserved exactly.
// ---------------------------------------------------------------------------
__global__ __launch_bounds__(256) void scan_k1(const ushort* __restrict__ lin,
                                               float4* __restrict__ agg) {
  int bd = blockIdx.x * 256 + threadIdx.x;    // 0..2047  (b*512 + d)
  int c  = blockIdx.y;                         // 0..127
  int b  = bd >> 9, d = bd & 511;
  const ushort* base = lin + ((size_t)b * 4096 + (size_t)c * 32) * 2048;
  float cth = 0.f, cbr = 0.f, cbi = 0.f;
  float cm = 1.f, cs = 1.f, sn = 0.f;
#pragma unroll 4
  for (int t = 0; t < 32; ++t) {
    const ushort* row = base + (size_t)t * 2048;
    float th = bf2f(row[d]);
    float z  = bf2f(row[512 + d]);
    float ir = bf2f(row[1024 + d]);
    float ii = bf2f(row[1536 + d]);
    float rt = __fdividef(1.f, 1.f + __expf(-z));
    cm *= fmaxf(rt, 1e-6f);
    cth += th;
    float s_, c_;
    __sincosf(cth, &s_, &c_);
    float im = __fdividef(1.f, fmaxf(cm, 1e-8f));
    float invr = im * c_, invi = -im * s_;
    float drive = 1.f - rt;
    float br_ = drive * ir, bi_ = drive * ii;
    cbr += invr * br_ - invi * bi_;
    cbi += invr * bi_ + invi * br_;
    cs = c_; sn = s_;
  }
  agg[(size_t)c * 2048 + bd] = make_float4(cm * cs, cm * sn, cbr, cbi);
}

__global__ __launch_bounds__(256) void scan_k2(const float4* __restrict__ agg,
                                               float2* __restrict__ h0) {
  int bd = blockIdx.x * 256 + threadIdx.x;    // 2048 threads
  float hr = 0.f, hi = 0.f;
  for (int cg = 0; cg < 16; ++cg) {
    float4 a[8];
#pragma unroll
    for (int u = 0; u < 8; ++u) a[u] = agg[(size_t)(cg * 8 + u) * 2048 + bd];
#pragma unroll
    for (int u = 0; u < 8; ++u) {
      h0[(size_t)(cg * 8 + u) * 2048 + bd] = make_float2(hr, hi);
      float tr = hr + a[u].z, ti = hi + a[u].w;
      hr = a[u].x * tr - a[u].y * ti;
      hi = a[u].x * ti + a[u].y * tr;
    }
  }
}

__global__ __launch_bounds__(256) void scan_k3(const ushort* __restrict__ lin,
                                               const float2* __restrict__ h0,
                                               ushort* __restrict__ outb) {
  int bd = blockIdx.x * 256 + threadIdx.x;
  int c  = blockIdx.y;
  int b  = bd >> 9, d = bd & 511;
  const ushort* base = lin + ((size_t)b * 4096 + (size_t)c * 32) * 2048;
  float2 h = h0[(size_t)c * 2048 + bd];
  float cth = 0.f, cbr = 0.f, cbi = 0.f, cm = 1.f;
#pragma unroll 4
  for (int t = 0; t < 32; ++t) {
    const ushort* row = base + (size_t)t * 2048;
    float th = bf2f(row[d]);
    float z  = bf2f(row[512 + d]);
    float ir = bf2f(row[1024 + d]);
    float ii = bf2f(row[1536 + d]);
    float rt = __fdividef(1.f, 1.f + __expf(-z));
    cm *= fmaxf(rt, 1e-6f);
    cth += th;
    float s_, c_;
    __sincosf(cth, &s_, &c_);
    float im = __fdividef(1.f, fmaxf(cm, 1e-8f));
    float invr = im * c_, invi = -im * s_;
    float drive = 1.f - rt;
    float br_ = drive * ir, bi_ = drive * ii;
    cbr += invr * br_ - invi * bi_;
    cbi += invr * bi_ + invi * br_;
    float ar = cm * c_, ai = cm * s_;
    float tr = h.x + cbr, ti = h.y + cbi;
    float orr = ar * tr - ai * ti;
    float oii = ar * ti + ai * tr;
    size_t rowo = ((size_t)b * 4096 + (size_t)c * 32 + t) * 1024;
    outb[rowo + d] = f2bf(orr);
    outb[rowo + 512 + d] = f2bf(oii);
  }
}

// ---------------------------------------------------------------------------
// LayerNorm, one WAVE per row (4 rows/block). y = yb(bf16) + x(f32 residual).
// ---------------------------------------------------------------------------
__global__ __launch_bounds__(256) void ln_k(const ushort* __restrict__ yb,
                                            const float* __restrict__ x,
                                            const float* __restrict__ gamma,
                                            const float* __restrict__ beta,
                                            float* __restrict__ out) {
  const int lane = threadIdx.x & 63;
  const size_t row = (size_t)blockIdx.x * 4 + (threadIdx.x >> 6);
  const ushort* yr = yb + row * 1024;
  const float* xr = x + row * 1024;
  float v[4][4];
  float s = 0.f, s2 = 0.f;
#pragma unroll
  for (int q = 0; q < 4; ++q) {
    ushort4 uy = *(const ushort4*)(yr + q * 256 + lane * 4);
    float4 fx = *(const float4*)(xr + q * 256 + lane * 4);
    v[q][0] = bf2f(uy.x) + fx.x;
    v[q][1] = bf2f(uy.y) + fx.y;
    v[q][2] = bf2f(uy.z) + fx.z;
    v[q][3] = bf2f(uy.w) + fx.w;
#pragma unroll
    for (int j = 0; j < 4; ++j) { s += v[q][j]; s2 += v[q][j] * v[q][j]; }
  }
#pragma unroll
  for (int off = 32; off > 0; off >>= 1) {
    s  += __shfl_xor(s, off);
    s2 += __shfl_xor(s2, off);
  }
  const float mu = s * (1.f / 1024.f);
  const float rstd = rsqrtf(s2 * (1.f / 1024.f) - mu * mu + 1e-5f);
#pragma unroll
  for (int q = 0; q < 4; ++q) {
    float4 gv = *(const float4*)(gamma + q * 256 + lane * 4);
    float4 bv = *(const float4*)(beta + q * 256 + lane * 4);
    float4 o;
    o.x = (v[q][0] - mu) * rstd * gv.x + bv.x;
    o.y = (v[q][1] - mu) * rstd * gv.y + bv.y;
    o.z = (v[q][2] - mu) * rstd * gv.z + bv.z;
    o.w = (v[q][3] - mu) * rstd * gv.w + bv.w;
    *(float4*)(out + row * 1024 + q * 256 + lane * 4) = o;
  }
}

// ---------------------------------------------------------------------------
extern "C" void kernel_launch(void* const* d_in, const int* in_sizes, int n_in,
                              void* d_out, int out_size, void* d_ws, size_t ws_size,
                              hipStream_t stream) {
  (void)in_sizes; (void)n_in; (void)out_size; (void)ws_size;
  const float* x  = (const float*)d_in[0];
  const float* Wt = (const float*)d_in[1];
  const float* bt = (const float*)d_in[2];
  const float* Wr = (const float*)d_in[3];
  const float* br = (const float*)d_in[4];
  const float* Wi = (const float*)d_in[5];
  const float* bi = (const float*)d_in[6];
  const float* Wo = (const float*)d_in[7];
  const float* bo = (const float*)d_in[8];
  const float* gamma = (const float*)d_in[9];
  const float* beta  = (const float*)d_in[10];

  char* ws = (char*)d_ws;
  ushort* wcat_t = (ushort*)(ws);                      //  4 MiB: [2048][1024] bf16
  ushort* wo_t   = (ushort*)(ws + ((size_t)4  << 20)); //  2 MiB: [1024][1024] bf16
  float*  bcat   = (float*) (ws + ((size_t)6  << 20)); //  8 KiB
  float4* agg    = (float4*)(ws + ((size_t)8  << 20)); //  4 MiB: [128][2048]
  float2* h0     = (float2*)(ws + ((size_t)12 << 20)); //  2 MiB: [128][2048]
  ushort* outb   = (ushort*)(ws + ((size_t)48 << 20)); // 32 MiB: scan out bf16
  ushort* linb   = (ushort*)(ws + ((size_t)80 << 20)); // 64 MiB: lin bf16
  ushort* yb     = (ushort*)(ws + ((size_t)80 << 20)); // 32 MiB: y bf16 (overlays dead linb)

  // weight prep (fused) + bias pack
  tconv_all<<<dim3(32, 32, 4), dim3(32, 8), 0, stream>>>(Wt, Wr, Wi, Wo, wcat_t, wo_t);
  pack_bias<<<8, 256, 0, stream>>>(bt, br, bi, bcat);

  // lin(bf16) = x(f32, converted in-kernel) @ [Wt|Wr|Wi] + [bt|br|bi]
  gemm256<true><<<512, 512, 0, stream>>>(x, wcat_t, linb, bcat, 16384, 2048, 1024, 8);

  // chunked complex scan
  scan_k1<<<dim3(8, 128), 256, 0, stream>>>(linb, agg);
  scan_k2<<<8, 256, 0, stream>>>(agg, h0);
  scan_k3<<<dim3(8, 128), 256, 0, stream>>>(linb, h0, outb);

  // yb(bf16) = out @ Wo + bo   (256 blocks, 1/CU)
  gemm256<false><<<256, 512, 0, stream>>>(outb, wo_t, yb, bo, 16384, 1024, 1024, 4);

  // layernorm(yb + x) -> d_out   (one wave per row, f32 residual)
  ln_k<<<4096, 256, 0, stream>>>(yb, x, gamma, beta, (float*)d_out);
}